// Round 1
// baseline (4951.291 us; speedup 1.0000x reference)
//
#include <hip/hip_runtime.h>
#include <hip/hip_bf16.h>
#include <cstdint>
#include <cstddef>

#define D_   1024
#define H_   2048
#define G_   4
#define EPG_ 2
#define NE_  8      // G*EPG
#define NH_  16
#define HD_  64
#define L_   4
#define V_   32000
#define NC_  32000
#define B_   2
#define S_   1024
#define T_   2048   // B*S

// ---------------------------------------------------------------- embed
__global__ __launch_bounds__(256) void embed_kernel(const int* __restrict__ x,
    const float* __restrict__ tok, const float* __restrict__ pos,
    float* __restrict__ h) {
  int t = blockIdx.x;
  int tid = threadIdx.x;
  int token = x[t];
  int s = t & (S_ - 1);
  float4 tv = *(const float4*)(tok + (size_t)token * D_ + tid * 4);
  float4 pv = *(const float4*)(pos + (size_t)s * D_ + tid * 4);
  float4 r;
  r.x = tv.x + pv.x; r.y = tv.y + pv.y; r.z = tv.z + pv.z; r.w = tv.w + pv.w;
  *(float4*)(h + (size_t)t * D_ + tid * 4) = r;
}

// ---------------------------------------------------------------- layernorm
__device__ __forceinline__ float block_sum256(float v, float* sbuf) {
  #pragma unroll
  for (int o = 32; o >= 1; o >>= 1) v += __shfl_xor(v, o, 64);
  int tid = threadIdx.x;
  if ((tid & 63) == 0) sbuf[tid >> 6] = v;
  __syncthreads();
  float r = sbuf[0] + sbuf[1] + sbuf[2] + sbuf[3];
  __syncthreads();
  return r;
}

__global__ __launch_bounds__(256) void ln_kernel(const float* __restrict__ X,
    const float* __restrict__ w, const float* __restrict__ b,
    float* __restrict__ Y) {
  __shared__ float sbuf[4];
  int t = blockIdx.x, tid = threadIdx.x;
  const float* xr = X + (size_t)t * D_;
  float4 v = *(const float4*)(xr + tid * 4);
  float sum = v.x + v.y + v.z + v.w;
  float m = block_sum256(sum, sbuf) * (1.0f / D_);
  float dx = v.x - m, dy = v.y - m, dz = v.z - m, dw = v.w - m;
  float vs = dx * dx + dy * dy + dz * dz + dw * dw;
  float var = block_sum256(vs, sbuf) * (1.0f / D_);
  float rs = rsqrtf(var + 1e-5f);
  float4 wv = *(const float4*)(w + tid * 4);
  float4 bv = *(const float4*)(b + tid * 4);
  float4 o;
  o.x = dx * rs * wv.x + bv.x;
  o.y = dy * rs * wv.y + bv.y;
  o.z = dz * rs * wv.z + bv.z;
  o.w = dw * rs * wv.w + bv.w;
  *(float4*)(Y + (size_t)t * D_ + tid * 4) = o;
}

// ---------------------------------------------------------------- shared GEMM inner tile
// As, Bs are [64][20]; thread (tx,ty) owns rows ty+16i, cols tx+16j.
__device__ __forceinline__ void tile_fma16(const float (*As)[20], const float (*Bs)[20],
                                           int tx, int ty, float acc[4][4]) {
  #pragma unroll
  for (int kk = 0; kk < 16; kk += 4) {
    float4 a[4], b[4];
    #pragma unroll
    for (int i = 0; i < 4; i++) a[i] = *(const float4*)&As[ty + 16 * i][kk];
    #pragma unroll
    for (int j = 0; j < 4; j++) b[j] = *(const float4*)&Bs[tx + 16 * j][kk];
    #pragma unroll
    for (int i = 0; i < 4; i++)
      #pragma unroll
      for (int j = 0; j < 4; j++)
        acc[i][j] += a[i].x * b[j].x + a[i].y * b[j].y +
                     a[i].z * b[j].z + a[i].w * b[j].w;
  }
}

// ---------------------------------------------------------------- C = A @ B^T + bias (+res)
// A [M,K] row-major, Bw [N,K] row-major. M,N multiples of 64, K multiple of 16.
template<bool RES>
__global__ __launch_bounds__(256) void gemm_bt_kernel(const float* __restrict__ A,
    const float* __restrict__ Bw, const float* __restrict__ bias,
    const float* __restrict__ res, float* __restrict__ C, int M, int N, int K) {
  __shared__ __align__(16) float As[64][20];
  __shared__ __align__(16) float Bs[64][20];
  int tid = threadIdx.x;
  int tx = tid & 15, ty = tid >> 4;
  int row0 = blockIdx.y * 64, col0 = blockIdx.x * 64;
  int lrow = tid >> 2, lk = (tid & 3) * 4;
  const float* aptr = A + (size_t)(row0 + lrow) * K + lk;
  const float* bptr = Bw + (size_t)(col0 + lrow) * K + lk;
  float acc[4][4] = {};
  for (int k0 = 0; k0 < K; k0 += 16) {
    float4 av = *(const float4*)(aptr + k0);
    float4 bv = *(const float4*)(bptr + k0);
    *(float4*)&As[lrow][lk] = av;
    *(float4*)&Bs[lrow][lk] = bv;
    __syncthreads();
    tile_fma16(As, Bs, tx, ty, acc);
    __syncthreads();
  }
  #pragma unroll
  for (int i = 0; i < 4; i++) {
    int r = row0 + ty + 16 * i;
    #pragma unroll
    for (int j = 0; j < 4; j++) {
      int c = col0 + tx + 16 * j;
      float v = acc[i][j] + bias[c];
      if (RES) v += res[(size_t)r * N + c];
      C[(size_t)r * N + c] = v;
    }
  }
}

// ---------------------------------------------------------------- flash attention fp32
// grid (S/64, B*NH), block 256. qkv: [B*S, 3*D], out: [B*S, D] (heads concat)
__global__ __launch_bounds__(256) void attn_kernel(const float* __restrict__ qkv,
                                                   float* __restrict__ out) {
  __shared__ __align__(16) float Qs[64][68];
  __shared__ __align__(16) float KVs[64][68];
  __shared__ __align__(16) float Ps[64][68];
  int qt = blockIdx.x;
  int bh = blockIdx.y;
  int b = bh >> 4, hh = bh & 15;
  int tid = threadIdx.x, tx = tid & 15, ty = tid >> 4;
  size_t base = (size_t)b * S_ * 3 * D_;
  int hoff = hh * HD_;

  #pragma unroll
  for (int it = 0; it < 4; it++) {
    int idx = tid + it * 256;
    int r = idx >> 4, d4 = (idx & 15) * 4;
    float4 v = *(const float4*)(qkv + base + (size_t)(qt * 64 + r) * 3 * D_ + hoff + d4);
    v.x *= 0.125f; v.y *= 0.125f; v.z *= 0.125f; v.w *= 0.125f;
    *(float4*)&Qs[r][d4] = v;
  }

  float o[4][4] = {};
  float mprev[4] = {-1e30f, -1e30f, -1e30f, -1e30f};
  float lsum[4] = {0.f, 0.f, 0.f, 0.f};

  for (int kt = 0; kt <= qt; kt++) {
    #pragma unroll
    for (int it = 0; it < 4; it++) {
      int idx = tid + it * 256;
      int r = idx >> 4, d4 = (idx & 15) * 4;
      *(float4*)&KVs[r][d4] =
          *(const float4*)(qkv + base + (size_t)(kt * 64 + r) * 3 * D_ + D_ + hoff + d4);
    }
    __syncthreads();

    float s[4][4] = {};
    #pragma unroll
    for (int d = 0; d < 64; d += 4) {
      float4 qv[4], kv[4];
      #pragma unroll
      for (int i = 0; i < 4; i++) qv[i] = *(const float4*)&Qs[ty + 16 * i][d];
      #pragma unroll
      for (int j = 0; j < 4; j++) kv[j] = *(const float4*)&KVs[tx + 16 * j][d];
      #pragma unroll
      for (int i = 0; i < 4; i++)
        #pragma unroll
        for (int j = 0; j < 4; j++)
          s[i][j] += qv[i].x * kv[j].x + qv[i].y * kv[j].y +
                     qv[i].z * kv[j].z + qv[i].w * kv[j].w;
    }
    if (kt == qt) {
      #pragma unroll
      for (int i = 0; i < 4; i++)
        #pragma unroll
        for (int j = 0; j < 4; j++)
          if (tx + 16 * j > ty + 16 * i) s[i][j] = -1e30f;
    }
    // online softmax per row (row group = 16 consecutive lanes)
    #pragma unroll
    for (int i = 0; i < 4; i++) {
      float rm = fmaxf(fmaxf(s[i][0], s[i][1]), fmaxf(s[i][2], s[i][3]));
      #pragma unroll
      for (int o2 = 8; o2 >= 1; o2 >>= 1) rm = fmaxf(rm, __shfl_xor(rm, o2, 64));
      float mnew = fmaxf(mprev[i], rm);
      float corr = __expf(mprev[i] - mnew);
      float rs = 0.f;
      #pragma unroll
      for (int j = 0; j < 4; j++) { s[i][j] = __expf(s[i][j] - mnew); rs += s[i][j]; }
      #pragma unroll
      for (int o2 = 8; o2 >= 1; o2 >>= 1) rs += __shfl_xor(rs, o2, 64);
      lsum[i] = lsum[i] * corr + rs;
      mprev[i] = mnew;
      #pragma unroll
      for (int j = 0; j < 4; j++) {
        o[i][j] *= corr;
        Ps[ty + 16 * i][tx + 16 * j] = s[i][j];
      }
    }
    __syncthreads();   // K reads + P writes complete
    #pragma unroll
    for (int it = 0; it < 4; it++) {
      int idx = tid + it * 256;
      int r = idx >> 4, d4 = (idx & 15) * 4;
      *(float4*)&KVs[r][d4] =
          *(const float4*)(qkv + base + (size_t)(kt * 64 + r) * 3 * D_ + 2 * D_ + hoff + d4);
    }
    __syncthreads();
    // O += P @ V
    #pragma unroll
    for (int kk = 0; kk < 64; kk += 4) {
      float4 pv[4];
      #pragma unroll
      for (int i = 0; i < 4; i++) pv[i] = *(const float4*)&Ps[ty + 16 * i][kk];
      #pragma unroll
      for (int q = 0; q < 4; q++) {
        float pq0, pq1, pq2, pq3;
        if (q == 0)      { pq0 = pv[0].x; pq1 = pv[1].x; pq2 = pv[2].x; pq3 = pv[3].x; }
        else if (q == 1) { pq0 = pv[0].y; pq1 = pv[1].y; pq2 = pv[2].y; pq3 = pv[3].y; }
        else if (q == 2) { pq0 = pv[0].z; pq1 = pv[1].z; pq2 = pv[2].z; pq3 = pv[3].z; }
        else             { pq0 = pv[0].w; pq1 = pv[1].w; pq2 = pv[2].w; pq3 = pv[3].w; }
        float v0 = KVs[kk + q][tx];
        float v1 = KVs[kk + q][tx + 16];
        float v2 = KVs[kk + q][tx + 32];
        float v3 = KVs[kk + q][tx + 48];
        o[0][0] += pq0 * v0; o[0][1] += pq0 * v1; o[0][2] += pq0 * v2; o[0][3] += pq0 * v3;
        o[1][0] += pq1 * v0; o[1][1] += pq1 * v1; o[1][2] += pq1 * v2; o[1][3] += pq1 * v3;
        o[2][0] += pq2 * v0; o[2][1] += pq2 * v1; o[2][2] += pq2 * v2; o[2][3] += pq2 * v3;
        o[3][0] += pq3 * v0; o[3][1] += pq3 * v1; o[3][2] += pq3 * v2; o[3][3] += pq3 * v3;
      }
    }
    __syncthreads();   // P/V reads complete before next tile overwrites
  }
  #pragma unroll
  for (int i = 0; i < 4; i++) {
    float inv = 1.0f / lsum[i];
    int srow = qt * 64 + ty + 16 * i;
    #pragma unroll
    for (int j = 0; j < 4; j++)
      out[((size_t)b * S_ + srow) * D_ + hoff + tx + 16 * j] = o[i][j] * inv;
  }
}

// ---------------------------------------------------------------- routing (1 wave / token)
__global__ __launch_bounds__(64) void route_kernel(const float* __restrict__ X,
    const float* __restrict__ gw, const float* __restrict__ gb,
    const float* __restrict__ ew, const float* __restrict__ eb,
    int* __restrict__ eidx, float* __restrict__ gate, int* __restrict__ counts) {
  int t = blockIdx.x;
  int lane = threadIdx.x;
  const float* xr = X + (size_t)t * D_;
  float g0 = 0, g1 = 0, g2 = 0, g3 = 0;
  #pragma unroll
  for (int k = 0; k < 16; k++) {
    int d = lane + 64 * k;
    float xv = xr[d];
    float4 gv = *(const float4*)(gw + (size_t)d * G_);
    g0 += xv * gv.x; g1 += xv * gv.y; g2 += xv * gv.z; g3 += xv * gv.w;
  }
  #pragma unroll
  for (int o = 32; o >= 1; o >>= 1) {
    g0 += __shfl_xor(g0, o, 64); g1 += __shfl_xor(g1, o, 64);
    g2 += __shfl_xor(g2, o, 64); g3 += __shfl_xor(g3, o, 64);
  }
  g0 += gb[0]; g1 += gb[1]; g2 += gb[2]; g3 += gb[3];
  float mx = fmaxf(fmaxf(g0, g1), fmaxf(g2, g3));
  float p0 = __expf(g0 - mx), p1 = __expf(g1 - mx), p2 = __expf(g2 - mx), p3 = __expf(g3 - mx);
  float psum = p0 + p1 + p2 + p3;
  int gidx = 0; float best = g0;
  if (g1 > best) { best = g1; gidx = 1; }
  if (g2 > best) { best = g2; gidx = 2; }
  if (g3 > best) { best = g3; gidx = 3; }
  float gpsel = ((gidx == 0) ? p0 : (gidx == 1) ? p1 : (gidx == 2) ? p2 : p3) / psum;

  const float* ewg = ew + (size_t)gidx * D_ * EPG_;
  float e0 = 0, e1 = 0;
  #pragma unroll
  for (int k = 0; k < 16; k++) {
    int d = lane + 64 * k;
    float xv = xr[d];
    float2 ev = *(const float2*)(ewg + (size_t)d * EPG_);
    e0 += xv * ev.x; e1 += xv * ev.y;
  }
  #pragma unroll
  for (int o = 32; o >= 1; o >>= 1) {
    e0 += __shfl_xor(e0, o, 64); e1 += __shfl_xor(e1, o, 64);
  }
  e0 += eb[gidx * EPG_ + 0]; e1 += eb[gidx * EPG_ + 1];
  float em = fmaxf(e0, e1);
  float q0 = __expf(e0 - em), q1 = __expf(e1 - em);
  int ei = (e1 > e0) ? 1 : 0;
  float epsel = ((ei == 0) ? q0 : q1) / (q0 + q1);
  if (lane == 0) {
    int e8 = gidx * EPG_ + ei;
    eidx[t] = e8;
    gate[t] = gpsel * epsel;
    atomicAdd(&counts[e8], 1);
  }
}

__global__ void zero_counts_kernel(int* __restrict__ counts) {
  if (threadIdx.x < NE_) counts[threadIdx.x] = 0;
}

__global__ void scan_kernel(const int* __restrict__ counts, int* __restrict__ offs,
                            int* __restrict__ fill) {
  if (threadIdx.x == 0) {
    int acc = 0;
    for (int e = 0; e < NE_; e++) { offs[e] = acc; fill[e] = acc; acc += counts[e]; }
  }
}

__global__ __launch_bounds__(256) void scatter_kernel(const int* __restrict__ eidx,
    int* __restrict__ fill, int* __restrict__ tlist) {
  int t = blockIdx.x * 256 + threadIdx.x;
  if (t >= T_) return;
  int e = eidx[t];
  int p = atomicAdd(&fill[e], 1);
  tlist[p] = t;
}

// ---------------------------------------------------------------- MoE expert GEMMs
// W1 [NE, D, H] (K-major, N contiguous); gathered rows of X [T,D]. hmid[token,H] = relu(x@W1+b1)
__global__ __launch_bounds__(256) void moe_w1_kernel(const float* __restrict__ X,
    const float* __restrict__ W1p, const float* __restrict__ B1p,
    const int* __restrict__ tlist, const int* __restrict__ offs,
    const int* __restrict__ counts, float* __restrict__ hmid) {
  __shared__ __align__(16) float As[64][20];
  __shared__ __align__(16) float Bs[64][20];
  int e = blockIdx.z;
  int cnt = counts[e];
  int mt = blockIdx.y;
  if (mt * 64 >= cnt) return;
  int tid = threadIdx.x, tx = tid & 15, ty = tid >> 4;
  int col0 = blockIdx.x * 64;
  const float* W = W1p + (size_t)e * D_ * H_;
  int base = offs[e];
  int lrow = tid >> 2, lk = (tid & 3) * 4;
  int ridx = mt * 64 + lrow;
  int tok = (ridx < cnt) ? tlist[base + ridx] : -1;
  int brow = tid >> 4, bcol = (tid & 15) * 4;
  float acc[4][4] = {};
  for (int k0 = 0; k0 < D_; k0 += 16) {
    float4 av = make_float4(0.f, 0.f, 0.f, 0.f);
    if (tok >= 0) av = *(const float4*)(X + (size_t)tok * D_ + k0 + lk);
    float4 bv = *(const float4*)(W + (size_t)(k0 + brow) * H_ + col0 + bcol);
    *(float4*)&As[lrow][lk] = av;
    Bs[bcol + 0][brow] = bv.x;
    Bs[bcol + 1][brow] = bv.y;
    Bs[bcol + 2][brow] = bv.z;
    Bs[bcol + 3][brow] = bv.w;
    __syncthreads();
    tile_fma16(As, Bs, tx, ty, acc);
    __syncthreads();
  }
  #pragma unroll
  for (int i = 0; i < 4; i++) {
    int r = mt * 64 + ty + 16 * i;
    if (r < cnt) {
      int tdst = tlist[base + r];
      #pragma unroll
      for (int j = 0; j < 4; j++) {
        int c = col0 + tx + 16 * j;
        float v = acc[i][j] + B1p[(size_t)e * H_ + c];
        hmid[(size_t)tdst * H_ + c] = fmaxf(v, 0.f);
      }
    }
  }
}

// W2 [NE, H, D]; h[token] += gate * (hmid@W2 + b2)
__global__ __launch_bounds__(256) void moe_w2_kernel(const float* __restrict__ Xh,
    const float* __restrict__ W2p, const float* __restrict__ B2p,
    const int* __restrict__ tlist, const int* __restrict__ offs,
    const int* __restrict__ counts, const float* __restrict__ gate,
    float* __restrict__ h) {
  __shared__ __align__(16) float As[64][20];
  __shared__ __align__(16) float Bs[64][20];
  int e = blockIdx.z;
  int cnt = counts[e];
  int mt = blockIdx.y;
  if (mt * 64 >= cnt) return;
  int tid = threadIdx.x, tx = tid & 15, ty = tid >> 4;
  int col0 = blockIdx.x * 64;
  const float* W = W2p + (size_t)e * H_ * D_;
  int base = offs[e];
  int lrow = tid >> 2, lk = (tid & 3) * 4;
  int ridx = mt * 64 + lrow;
  int tok = (ridx < cnt) ? tlist[base + ridx] : -1;
  int brow = tid >> 4, bcol = (tid & 15) * 4;
  float acc[4][4] = {};
  for (int k0 = 0; k0 < H_; k0 += 16) {
    float4 av = make_float4(0.f, 0.f, 0.f, 0.f);
    if (tok >= 0) av = *(const float4*)(Xh + (size_t)tok * H_ + k0 + lk);
    float4 bv = *(const float4*)(W + (size_t)(k0 + brow) * D_ + col0 + bcol);
    *(float4*)&As[lrow][lk] = av;
    Bs[bcol + 0][brow] = bv.x;
    Bs[bcol + 1][brow] = bv.y;
    Bs[bcol + 2][brow] = bv.z;
    Bs[bcol + 3][brow] = bv.w;
    __syncthreads();
    tile_fma16(As, Bs, tx, ty, acc);
    __syncthreads();
  }
  #pragma unroll
  for (int i = 0; i < 4; i++) {
    int r = mt * 64 + ty + 16 * i;
    if (r < cnt) {
      int tdst = tlist[base + r];
      float gv = gate[tdst];
      #pragma unroll
      for (int j = 0; j < 4; j++) {
        int c = col0 + tx + 16 * j;
        float v = gv * (acc[i][j] + B2p[(size_t)e * D_ + c]);
        h[(size_t)tdst * D_ + c] += v;
      }
    }
  }
}

// ---------------------------------------------------------------- final mean + head
__global__ __launch_bounds__(256) void mean_part_kernel(const float* __restrict__ X,
                                                        float* __restrict__ part) {
  int bd = blockIdx.x * 256 + threadIdx.x;   // 0..2047
  int chunk = blockIdx.y;                    // 0..15
  int b = bd >> 10, d = bd & 1023;
  float s = 0.f;
  #pragma unroll 4
  for (int i = 0; i < 64; i++) {
    int sidx = chunk * 64 + i;
    s += X[((size_t)b * S_ + sidx) * D_ + d];
  }
  part[chunk * T_ + bd] = s;
}

__global__ __launch_bounds__(256) void mean_final_kernel(const float* __restrict__ part,
                                                         float* __restrict__ hm) {
  int bd = blockIdx.x * 256 + threadIdx.x;
  float s = 0.f;
  #pragma unroll
  for (int c = 0; c < 16; c++) s += part[c * T_ + bd];
  hm[bd] = s * (1.0f / S_);
}

// one wave per class; hm kept in registers
__global__ __launch_bounds__(256) void head_kernel(const float* __restrict__ hm,
    const float* __restrict__ hw, const float* __restrict__ hb,
    float* __restrict__ out) {
  int w = threadIdx.x >> 6;
  int lane = threadIdx.x & 63;
  int c = blockIdx.x * 4 + w;
  const float* row = hw + (size_t)c * D_;
  float acc0 = 0.f, acc1 = 0.f;
  #pragma unroll
  for (int k = 0; k < 4; k++) {
    int d = lane * 4 + k * 256;
    float4 wv = *(const float4*)(row + d);
    float4 h0 = *(const float4*)(hm + d);
    float4 h1 = *(const float4*)(hm + D_ + d);
    acc0 += wv.x * h0.x + wv.y * h0.y + wv.z * h0.z + wv.w * h0.w;
    acc1 += wv.x * h1.x + wv.y * h1.y + wv.z * h1.z + wv.w * h1.w;
  }
  #pragma unroll
  for (int o = 32; o >= 1; o >>= 1) {
    acc0 += __shfl_xor(acc0, o, 64);
    acc1 += __shfl_xor(acc1, o, 64);
  }
  if (lane == 0) {
    float bias = hb[c];
    out[c] = acc0 + bias;
    out[NC_ + c] = acc1 + bias;
  }
}

// ---------------------------------------------------------------- host launch
extern "C" void kernel_launch(void* const* d_in, const int* in_sizes, int n_in,
                              void* d_out, int out_size, void* d_ws, size_t ws_size,
                              hipStream_t stream) {
  const int*   x        = (const int*)d_in[0];
  const float* tok_emb  = (const float*)d_in[1];
  const float* pos_emb  = (const float*)d_in[2];
  const float* in_proj_w= (const float*)d_in[3];
  const float* in_proj_b= (const float*)d_in[4];
  const float* out_w    = (const float*)d_in[5];
  const float* out_b    = (const float*)d_in[6];
  const float* ln1_w    = (const float*)d_in[7];
  const float* ln1_b    = (const float*)d_in[8];
  const float* ln2_w    = (const float*)d_in[9];
  const float* ln2_b    = (const float*)d_in[10];
  const float* gr_w     = (const float*)d_in[11];
  const float* gr_b     = (const float*)d_in[12];
  const float* er_w     = (const float*)d_in[13];
  const float* er_b     = (const float*)d_in[14];
  const float* w1       = (const float*)d_in[15];
  const float* b1       = (const float*)d_in[16];
  const float* w2       = (const float*)d_in[17];
  const float* b2       = (const float*)d_in[18];
  const float* lnf_w    = (const float*)d_in[19];
  const float* lnf_b    = (const float*)d_in[20];
  const float* head_w   = (const float*)d_in[21];
  const float* head_b   = (const float*)d_in[22];

  float* ws = (float*)d_ws;
  float* h        = ws;                       // T*D
  float* x1       = h + (size_t)T_ * D_;      // T*D
  float* qkv      = x1 + (size_t)T_ * D_;     // T*3D
  float* hmid     = qkv;                      // alias: T*H (qkv dead when MoE runs)
  float* attn_out = qkv + (size_t)T_ * 3 * D_;// T*D
  float* part     = attn_out + (size_t)T_ * D_; // 16*T
  float* hm       = part + 16 * T_;           // T (uses B*D = 2048)
  float* gate     = hm + T_;                  // T
  int*   eidx     = (int*)(gate + T_);        // T
  int*   tlist    = eidx + T_;                // T
  int*   counts   = tlist + T_;               // 8
  int*   offs     = counts + NE_;             // 8
  int*   fill     = offs + NE_;               // 8

  embed_kernel<<<T_, 256, 0, stream>>>(x, tok_emb, pos_emb, h);

  for (int l = 0; l < L_; l++) {
    ln_kernel<<<T_, 256, 0, stream>>>(h, ln1_w + l * D_, ln1_b + l * D_, x1);
    gemm_bt_kernel<false><<<dim3(48, 32), 256, 0, stream>>>(
        x1, in_proj_w + (size_t)l * 3 * D_ * D_, in_proj_b + (size_t)l * 3 * D_,
        nullptr, qkv, T_, 3 * D_, D_);
    attn_kernel<<<dim3(S_ / 64, B_ * NH_), 256, 0, stream>>>(qkv, attn_out);
    gemm_bt_kernel<true><<<dim3(16, 32), 256, 0, stream>>>(
        attn_out, out_w + (size_t)l * D_ * D_, out_b + (size_t)l * D_,
        h, h, T_, D_, D_);
    ln_kernel<<<T_, 256, 0, stream>>>(h, ln2_w + l * D_, ln2_b + l * D_, x1);
    zero_counts_kernel<<<1, 64, 0, stream>>>(counts);
    route_kernel<<<T_, 64, 0, stream>>>(x1,
        gr_w + (size_t)l * D_ * G_, gr_b + (size_t)l * G_,
        er_w + (size_t)l * G_ * D_ * EPG_, er_b + (size_t)l * G_ * EPG_,
        eidx, gate, counts);
    scan_kernel<<<1, 1, 0, stream>>>(counts, offs, fill);
    scatter_kernel<<<T_ / 256, 256, 0, stream>>>(eidx, fill, tlist);
    moe_w1_kernel<<<dim3(H_ / 64, T_ / 64, NE_), 256, 0, stream>>>(
        x1, w1 + (size_t)l * NE_ * D_ * H_, b1 + (size_t)l * NE_ * H_,
        tlist, offs, counts, hmid);
    moe_w2_kernel<<<dim3(D_ / 64, T_ / 64, NE_), 256, 0, stream>>>(
        hmid, w2 + (size_t)l * NE_ * H_ * D_, b2 + (size_t)l * NE_ * D_,
        tlist, offs, counts, gate, h);
  }

  ln_kernel<<<T_, 256, 0, stream>>>(h, lnf_w, lnf_b, x1);
  mean_part_kernel<<<dim3(B_ * D_ / 256, 16), 256, 0, stream>>>(x1, part);
  mean_final_kernel<<<B_ * D_ / 256, 256, 0, stream>>>(part, hm);
  head_kernel<<<NC_ / 4, 256, 0, stream>>>(hm, head_w, head_b, (float*)d_out);
}

// Round 2
// 1554.892 us; speedup vs baseline: 3.1843x; 3.1843x over previous
//
#include <hip/hip_runtime.h>
#include <hip/hip_bf16.h>
#include <cstdint>
#include <cstddef>

#define D_   1024
#define H_   2048
#define G_   4
#define EPG_ 2
#define NE_  8      // G*EPG
#define NH_  16
#define HD_  64
#define L_   4
#define V_   32000
#define NC_  32000
#define B_   2
#define S_   1024
#define T_   2048   // B*S

typedef __attribute__((__ext_vector_type__(8))) __bf16 bf16x8;
typedef __attribute__((__ext_vector_type__(4))) __bf16 bf16x4;
typedef __attribute__((__ext_vector_type__(4))) float  f32x4;

// ---------------------------------------------------------------- embed
__global__ __launch_bounds__(256) void embed_kernel(const int* __restrict__ x,
    const float* __restrict__ tok, const float* __restrict__ pos,
    float* __restrict__ h) {
  int t = blockIdx.x;
  int tid = threadIdx.x;
  int token = x[t];
  int s = t & (S_ - 1);
  float4 tv = *(const float4*)(tok + (size_t)token * D_ + tid * 4);
  float4 pv = *(const float4*)(pos + (size_t)s * D_ + tid * 4);
  float4 r;
  r.x = tv.x + pv.x; r.y = tv.y + pv.y; r.z = tv.z + pv.z; r.w = tv.w + pv.w;
  *(float4*)(h + (size_t)t * D_ + tid * 4) = r;
}

// ---------------------------------------------------------------- layernorm
__device__ __forceinline__ float block_sum256(float v, float* sbuf) {
  #pragma unroll
  for (int o = 32; o >= 1; o >>= 1) v += __shfl_xor(v, o, 64);
  int tid = threadIdx.x;
  if ((tid & 63) == 0) sbuf[tid >> 6] = v;
  __syncthreads();
  float r = sbuf[0] + sbuf[1] + sbuf[2] + sbuf[3];
  __syncthreads();
  return r;
}

template<bool F32OUT, bool BFOUT>
__global__ __launch_bounds__(256) void ln_kernel(const float* __restrict__ X,
    const float* __restrict__ w, const float* __restrict__ b,
    float* __restrict__ Yf, __bf16* __restrict__ Yb) {
  __shared__ float sbuf[4];
  int t = blockIdx.x, tid = threadIdx.x;
  const float* xr = X + (size_t)t * D_;
  float4 v = *(const float4*)(xr + tid * 4);
  float sum = v.x + v.y + v.z + v.w;
  float m = block_sum256(sum, sbuf) * (1.0f / D_);
  float dx = v.x - m, dy = v.y - m, dz = v.z - m, dw = v.w - m;
  float vs = dx * dx + dy * dy + dz * dz + dw * dw;
  float var = block_sum256(vs, sbuf) * (1.0f / D_);
  float rs = rsqrtf(var + 1e-5f);
  float4 wv = *(const float4*)(w + tid * 4);
  float4 bv = *(const float4*)(b + tid * 4);
  float4 o;
  o.x = dx * rs * wv.x + bv.x;
  o.y = dy * rs * wv.y + bv.y;
  o.z = dz * rs * wv.z + bv.z;
  o.w = dw * rs * wv.w + bv.w;
  if (F32OUT) *(float4*)(Yf + (size_t)t * D_ + tid * 4) = o;
  if (BFOUT) {
    bf16x4 ob = {(__bf16)o.x, (__bf16)o.y, (__bf16)o.z, (__bf16)o.w};
    *(bf16x4*)(Yb + (size_t)t * D_ + tid * 4) = ob;
  }
}

// ---------------------------------------------------------------- fp32 -> bf16 flat convert
__global__ __launch_bounds__(256) void conv_bf16_kernel(const float* __restrict__ in,
    __bf16* __restrict__ out, int n) {
  int i = (blockIdx.x * 256 + threadIdx.x) * 4;
  if (i >= n) return;
  float4 v = *(const float4*)(in + i);
  bf16x4 o = {(__bf16)v.x, (__bf16)v.y, (__bf16)v.z, (__bf16)v.w};
  *(bf16x4*)(out + i) = o;
}

// ---------------------------------------------------------------- transpose + convert: src [M,N] f32 -> dst [N,M] bf16, per expert z
__global__ __launch_bounds__(256) void transpose_conv_kernel(const float* __restrict__ src,
    __bf16* __restrict__ dst, int M, int N) {
  __shared__ float tile[64][65];
  int e = blockIdx.z;
  src += (size_t)e * M * N;
  dst += (size_t)e * M * N;
  int r0 = blockIdx.y * 64;   // row in src (M dim)
  int c0 = blockIdx.x * 64;   // col in src (N dim)
  int tid = threadIdx.x;
  #pragma unroll
  for (int it = 0; it < 16; it++) {
    int idx = tid + it * 256;
    int r = idx >> 6, c = idx & 63;
    tile[r][c] = src[(size_t)(r0 + r) * N + c0 + c];
  }
  __syncthreads();
  #pragma unroll
  for (int it = 0; it < 16; it++) {
    int idx = tid + it * 256;
    int r = idx >> 6, c = idx & 63;   // r: N-dim offset, c: M-dim offset
    dst[(size_t)(c0 + r) * M + r0 + c] = (__bf16)tile[c][r];
  }
}

// ---------------------------------------------------------------- bf16 MFMA GEMM: C[M,N] = A[M,K] @ W[N,K]^T + bias
// MODE 0: Cb = acc+bias (bf16 out)            [qkv]
// MODE 1: Cf += acc+bias (f32 residual)       [out-proj]
// MODE 2: gather rows; Cb = relu(acc+bias)    [moe w1]
// MODE 3: gather rows; Cf += gate*(acc+bias)  [moe w2]
template<int MODE>
__global__ __launch_bounds__(256) void gemm_mfma(
    const __bf16* __restrict__ A, const __bf16* __restrict__ W,
    const float* __restrict__ bias, float* __restrict__ Cf,
    __bf16* __restrict__ Cb, const int* __restrict__ tlist,
    const int* __restrict__ offs, const int* __restrict__ counts,
    const float* __restrict__ gate, int N, int K) {
  __shared__ __bf16 As[128][72];
  __shared__ __bf16 Bs[64][72];
  int e = blockIdx.z;
  int cnt = (MODE >= 2) ? counts[e] : T_;
  int row0 = blockIdx.y * 128;
  if (row0 >= cnt) return;
  int lbase = (MODE >= 2) ? offs[e] : 0;
  int col0 = blockIdx.x * 64;
  const __bf16* Wp = W + (size_t)e * N * K;
  const float* bp = bias + (size_t)e * N;
  int tid = threadIdx.x;
  int w = tid >> 6, lane = tid & 63, lq = lane & 15, lg = lane >> 4;
  int wr = w >> 1, wc = w & 1;
  int c8 = tid & 7, srow = tid >> 3;

  long arow[4];
  #pragma unroll
  for (int it = 0; it < 4; it++) {
    int gr = row0 + srow + it * 32;
    if (MODE >= 2) arow[it] = (gr < cnt) ? (long)tlist[lbase + gr] : -1;
    else arow[it] = gr;
  }

  f32x4 acc[4][2] = {};
  for (int k0 = 0; k0 < K; k0 += 64) {
    #pragma unroll
    for (int it = 0; it < 4; it++) {
      bf16x8 av = {};
      if (arow[it] >= 0) av = *(const bf16x8*)(A + arow[it] * K + k0 + c8 * 8);
      *(bf16x8*)&As[srow + it * 32][c8 * 8] = av;
    }
    #pragma unroll
    for (int it = 0; it < 2; it++) {
      int r = srow + it * 32;
      *(bf16x8*)&Bs[r][c8 * 8] = *(const bf16x8*)(Wp + (size_t)(col0 + r) * K + k0 + c8 * 8);
    }
    __syncthreads();
    #pragma unroll
    for (int kk = 0; kk < 2; kk++) {
      bf16x8 a[4], b[2];
      #pragma unroll
      for (int fi = 0; fi < 4; fi++)
        a[fi] = *(const bf16x8*)&As[wr * 64 + fi * 16 + lq][lg * 8 + kk * 32];
      #pragma unroll
      for (int fj = 0; fj < 2; fj++)
        b[fj] = *(const bf16x8*)&Bs[wc * 32 + fj * 16 + lq][lg * 8 + kk * 32];
      #pragma unroll
      for (int fi = 0; fi < 4; fi++)
        #pragma unroll
        for (int fj = 0; fj < 2; fj++)
          acc[fi][fj] = __builtin_amdgcn_mfma_f32_16x16x32_bf16(a[fi], b[fj], acc[fi][fj], 0, 0, 0);
    }
    __syncthreads();
  }

  #pragma unroll
  for (int fi = 0; fi < 4; fi++) {
    #pragma unroll
    for (int v = 0; v < 4; v++) {
      int r = row0 + wr * 64 + fi * 16 + lg * 4 + v;
      long orow;
      float gv = 1.f;
      if (MODE >= 2) {
        if (r >= cnt) continue;
        orow = tlist[lbase + r];
        if (MODE == 3) gv = gate[orow];
      } else {
        orow = r;
      }
      #pragma unroll
      for (int fj = 0; fj < 2; fj++) {
        int c = col0 + wc * 32 + fj * 16 + lq;
        float val = acc[fi][fj][v] + bp[c];
        if (MODE == 0)      Cb[orow * N + c] = (__bf16)val;
        else if (MODE == 1) Cf[orow * N + c] += val;
        else if (MODE == 2) Cb[orow * N + c] = (__bf16)fmaxf(val, 0.f);
        else                Cf[orow * N + c] += gv * val;
      }
    }
  }
}

// ---------------------------------------------------------------- flash attention, bf16 MFMA
// grid (S/64, B*NH), 256 thr = 4 waves; each wave owns 16 query rows.
__global__ __launch_bounds__(256) void attn_mfma_kernel(const __bf16* __restrict__ qkv,
                                                        __bf16* __restrict__ out) {
  __shared__ __bf16 Ks[64][72];
  __shared__ __bf16 Vt[64][72];   // transposed: [d][kv]
  __shared__ __bf16 Ps[64][72];
  int tid = threadIdx.x;
  int w = tid >> 6, lane = tid & 63, lq = lane & 15, lg = lane >> 4;
  int qt = blockIdx.x, b = blockIdx.y >> 4, hh = blockIdx.y & 15;
  const __bf16* qbase = qkv + (size_t)b * S_ * 3 * D_ + hh * HD_;

  // Q fragments in registers (A operand: row=lq, k=lg*8+j, two 32-chunks)
  bf16x8 qa[2];
  {
    const __bf16* qp = qbase + (size_t)(qt * 64 + w * 16 + lq) * 3 * D_ + lg * 8;
    qa[0] = *(const bf16x8*)qp;
    qa[1] = *(const bf16x8*)(qp + 32);
  }

  f32x4 o[4] = {};
  float m_[4] = {-1e30f, -1e30f, -1e30f, -1e30f};
  float l_[4] = {0.f, 0.f, 0.f, 0.f};

  for (int kt = 0; kt <= qt; kt++) {
    // stage K (row-major) and V (transposed)
    #pragma unroll
    for (int it = 0; it < 2; it++) {
      int idx = tid + it * 256;
      int row = idx >> 3, c8 = idx & 7;
      const __bf16* kp = qbase + (size_t)(kt * 64 + row) * 3 * D_ + D_ + c8 * 8;
      *(bf16x8*)&Ks[row][c8 * 8] = *(const bf16x8*)kp;
      bf16x8 vv = *(const bf16x8*)(kp + D_);
      #pragma unroll
      for (int j = 0; j < 8; j++) Vt[c8 * 8 + j][row] = vv[j];
    }
    __syncthreads();

    // S = Q @ K^T   (B operand from Ks rows: col=kv=lq, k=d contiguous)
    f32x4 s[4] = {};
    #pragma unroll
    for (int kk = 0; kk < 2; kk++)
      #pragma unroll
      for (int fc = 0; fc < 4; fc++) {
        bf16x8 kf = *(const bf16x8*)&Ks[fc * 16 + lq][lg * 8 + kk * 32];
        s[fc] = __builtin_amdgcn_mfma_f32_16x16x32_bf16(qa[kk], kf, s[fc], 0, 0, 0);
      }

    // scale + causal mask
    #pragma unroll
    for (int fc = 0; fc < 4; fc++)
      #pragma unroll
      for (int v = 0; v < 4; v++) {
        float sv = s[fc][v] * 0.125f;
        if (kt == qt && (fc * 16 + lq) > (w * 16 + lg * 4 + v)) sv = -1e30f;
        s[fc][v] = sv;
      }

    // online softmax (rows live in 16-lane groups)
    float corr[4];
    #pragma unroll
    for (int v = 0; v < 4; v++) {
      float rm = fmaxf(fmaxf(s[0][v], s[1][v]), fmaxf(s[2][v], s[3][v]));
      #pragma unroll
      for (int o2 = 8; o2 >= 1; o2 >>= 1) rm = fmaxf(rm, __shfl_xor(rm, o2, 64));
      float mnew = fmaxf(m_[v], rm);
      float cc = __expf(m_[v] - mnew);
      float rs = 0.f;
      #pragma unroll
      for (int fc = 0; fc < 4; fc++) {
        float p = __expf(s[fc][v] - mnew);
        s[fc][v] = p; rs += p;
      }
      #pragma unroll
      for (int o2 = 8; o2 >= 1; o2 >>= 1) rs += __shfl_xor(rs, o2, 64);
      l_[v] = l_[v] * cc + rs;
      m_[v] = mnew;
      corr[v] = cc;
    }
    #pragma unroll
    for (int dc = 0; dc < 4; dc++)
      #pragma unroll
      for (int v = 0; v < 4; v++) o[dc][v] *= corr[v];

    // write P (bf16) to LDS in A-operand layout rows
    #pragma unroll
    for (int fc = 0; fc < 4; fc++)
      #pragma unroll
      for (int v = 0; v < 4; v++)
        Ps[w * 16 + lg * 4 + v][fc * 16 + lq] = (__bf16)s[fc][v];
    __syncthreads();

    // O += P @ V  (A = P rows of this wave; B = Vt rows = d, k = kv contiguous)
    #pragma unroll
    for (int kk = 0; kk < 2; kk++) {
      bf16x8 pa = *(const bf16x8*)&Ps[w * 16 + lq][lg * 8 + kk * 32];
      #pragma unroll
      for (int dc = 0; dc < 4; dc++) {
        bf16x8 vb = *(const bf16x8*)&Vt[dc * 16 + lq][lg * 8 + kk * 32];
        o[dc] = __builtin_amdgcn_mfma_f32_16x16x32_bf16(pa, vb, o[dc], 0, 0, 0);
      }
    }
    __syncthreads();
  }

  // epilogue: normalize, write bf16
  #pragma unroll
  for (int v = 0; v < 4; v++) {
    float inv = 1.0f / l_[v];
    int row = qt * 64 + w * 16 + lg * 4 + v;
    __bf16* op = out + ((size_t)b * S_ + row) * D_ + hh * HD_;
    #pragma unroll
    for (int dc = 0; dc < 4; dc++)
      op[dc * 16 + lq] = (__bf16)(o[dc][v] * inv);
  }
}

// ---------------------------------------------------------------- routing (1 wave / token, fp32)
__global__ __launch_bounds__(64) void route_kernel(const float* __restrict__ X,
    const float* __restrict__ gw, const float* __restrict__ gb,
    const float* __restrict__ ew, const float* __restrict__ eb,
    int* __restrict__ eidx, float* __restrict__ gate, int* __restrict__ counts) {
  int t = blockIdx.x;
  int lane = threadIdx.x;
  const float* xr = X + (size_t)t * D_;
  float g0 = 0, g1 = 0, g2 = 0, g3 = 0;
  #pragma unroll
  for (int k = 0; k < 16; k++) {
    int d = lane + 64 * k;
    float xv = xr[d];
    float4 gv = *(const float4*)(gw + (size_t)d * G_);
    g0 += xv * gv.x; g1 += xv * gv.y; g2 += xv * gv.z; g3 += xv * gv.w;
  }
  #pragma unroll
  for (int o = 32; o >= 1; o >>= 1) {
    g0 += __shfl_xor(g0, o, 64); g1 += __shfl_xor(g1, o, 64);
    g2 += __shfl_xor(g2, o, 64); g3 += __shfl_xor(g3, o, 64);
  }
  g0 += gb[0]; g1 += gb[1]; g2 += gb[2]; g3 += gb[3];
  float mx = fmaxf(fmaxf(g0, g1), fmaxf(g2, g3));
  float p0 = __expf(g0 - mx), p1 = __expf(g1 - mx), p2 = __expf(g2 - mx), p3 = __expf(g3 - mx);
  float psum = p0 + p1 + p2 + p3;
  int gidx = 0; float best = g0;
  if (g1 > best) { best = g1; gidx = 1; }
  if (g2 > best) { best = g2; gidx = 2; }
  if (g3 > best) { best = g3; gidx = 3; }
  float gpsel = ((gidx == 0) ? p0 : (gidx == 1) ? p1 : (gidx == 2) ? p2 : p3) / psum;

  const float* ewg = ew + (size_t)gidx * D_ * EPG_;
  float e0 = 0, e1 = 0;
  #pragma unroll
  for (int k = 0; k < 16; k++) {
    int d = lane + 64 * k;
    float xv = xr[d];
    float2 ev = *(const float2*)(ewg + (size_t)d * EPG_);
    e0 += xv * ev.x; e1 += xv * ev.y;
  }
  #pragma unroll
  for (int o = 32; o >= 1; o >>= 1) {
    e0 += __shfl_xor(e0, o, 64); e1 += __shfl_xor(e1, o, 64);
  }
  e0 += eb[gidx * EPG_ + 0]; e1 += eb[gidx * EPG_ + 1];
  float em = fmaxf(e0, e1);
  float q0 = __expf(e0 - em), q1 = __expf(e1 - em);
  int ei = (e1 > e0) ? 1 : 0;
  float epsel = ((ei == 0) ? q0 : q1) / (q0 + q1);
  if (lane == 0) {
    int e8 = gidx * EPG_ + ei;
    eidx[t] = e8;
    gate[t] = gpsel * epsel;
    atomicAdd(&counts[e8], 1);
  }
}

__global__ void zero_counts_kernel(int* __restrict__ counts) {
  if (threadIdx.x < NE_) counts[threadIdx.x] = 0;
}

__global__ void scan_kernel(const int* __restrict__ counts, int* __restrict__ offs,
                            int* __restrict__ fill) {
  if (threadIdx.x == 0) {
    int acc = 0;
    for (int e = 0; e < NE_; e++) { offs[e] = acc; fill[e] = acc; acc += counts[e]; }
  }
}

__global__ __launch_bounds__(256) void scatter_kernel(const int* __restrict__ eidx,
    int* __restrict__ fill, int* __restrict__ tlist) {
  int t = blockIdx.x * 256 + threadIdx.x;
  if (t >= T_) return;
  int e = eidx[t];
  int p = atomicAdd(&fill[e], 1);
  tlist[p] = t;
}

// ---------------------------------------------------------------- final mean + head (fp32)
__global__ __launch_bounds__(256) void mean_part_kernel(const float* __restrict__ X,
                                                        float* __restrict__ part) {
  int bd = blockIdx.x * 256 + threadIdx.x;
  int chunk = blockIdx.y;
  int b = bd >> 10, d = bd & 1023;
  float s = 0.f;
  #pragma unroll 4
  for (int i = 0; i < 64; i++) {
    int sidx = chunk * 64 + i;
    s += X[((size_t)b * S_ + sidx) * D_ + d];
  }
  part[chunk * T_ + bd] = s;
}

__global__ __launch_bounds__(256) void mean_final_kernel(const float* __restrict__ part,
                                                         float* __restrict__ hm) {
  int bd = blockIdx.x * 256 + threadIdx.x;
  float s = 0.f;
  #pragma unroll
  for (int c = 0; c < 16; c++) s += part[c * T_ + bd];
  hm[bd] = s * (1.0f / S_);
}

__global__ __launch_bounds__(256) void head_kernel(const float* __restrict__ hm,
    const float* __restrict__ hw, const float* __restrict__ hb,
    float* __restrict__ out) {
  int w = threadIdx.x >> 6;
  int lane = threadIdx.x & 63;
  int c = blockIdx.x * 4 + w;
  const float* row = hw + (size_t)c * D_;
  float acc0 = 0.f, acc1 = 0.f;
  #pragma unroll
  for (int k = 0; k < 4; k++) {
    int d = lane * 4 + k * 256;
    float4 wv = *(const float4*)(row + d);
    float4 h0 = *(const float4*)(hm + d);
    float4 h1 = *(const float4*)(hm + D_ + d);
    acc0 += wv.x * h0.x + wv.y * h0.y + wv.z * h0.z + wv.w * h0.w;
    acc1 += wv.x * h1.x + wv.y * h1.y + wv.z * h1.z + wv.w * h1.w;
  }
  #pragma unroll
  for (int o = 32; o >= 1; o >>= 1) {
    acc0 += __shfl_xor(acc0, o, 64);
    acc1 += __shfl_xor(acc1, o, 64);
  }
  if (lane == 0) {
    float bias = hb[c];
    out[c] = acc0 + bias;
    out[NC_ + c] = acc1 + bias;
  }
}

// ---------------------------------------------------------------- host launch
extern "C" void kernel_launch(void* const* d_in, const int* in_sizes, int n_in,
                              void* d_out, int out_size, void* d_ws, size_t ws_size,
                              hipStream_t stream) {
  const int*   x        = (const int*)d_in[0];
  const float* tok_emb  = (const float*)d_in[1];
  const float* pos_emb  = (const float*)d_in[2];
  const float* in_proj_w= (const float*)d_in[3];
  const float* in_proj_b= (const float*)d_in[4];
  const float* out_w    = (const float*)d_in[5];
  const float* out_b    = (const float*)d_in[6];
  const float* ln1_w    = (const float*)d_in[7];
  const float* ln1_b    = (const float*)d_in[8];
  const float* ln2_w    = (const float*)d_in[9];
  const float* ln2_b    = (const float*)d_in[10];
  const float* gr_w     = (const float*)d_in[11];
  const float* gr_b     = (const float*)d_in[12];
  const float* er_w     = (const float*)d_in[13];
  const float* er_b     = (const float*)d_in[14];
  const float* w1       = (const float*)d_in[15];
  const float* b1       = (const float*)d_in[16];
  const float* w2       = (const float*)d_in[17];
  const float* b2       = (const float*)d_in[18];
  const float* lnf_w    = (const float*)d_in[19];
  const float* lnf_b    = (const float*)d_in[20];
  const float* head_w   = (const float*)d_in[21];
  const float* head_b   = (const float*)d_in[22];

  char* wp = (char*)d_ws;
  auto carve = [&](size_t bytes) -> char* {
    char* p = wp;
    wp += (bytes + 255) & ~(size_t)255;
    return p;
  };
  float*  h      = (float*)carve((size_t)T_ * D_ * 4);
  float*  x1     = (float*)carve((size_t)T_ * D_ * 4);
  __bf16* x1b    = (__bf16*)carve((size_t)T_ * D_ * 2);
  __bf16* qkvb   = (__bf16*)carve((size_t)T_ * 3 * D_ * 2);
  __bf16* attnb  = (__bf16*)carve((size_t)T_ * D_ * 2);
  __bf16* hmidb  = (__bf16*)carve((size_t)T_ * H_ * 2);
  __bf16* wqb    = (__bf16*)carve((size_t)3 * D_ * D_ * 2);
  __bf16* wob    = (__bf16*)carve((size_t)D_ * D_ * 2);
  __bf16* wmb    = (__bf16*)carve((size_t)NE_ * D_ * H_ * 2);
  float*  part   = (float*)carve((size_t)16 * T_ * 4);
  float*  hm     = (float*)carve((size_t)B_ * D_ * 4);
  float*  gate   = (float*)carve((size_t)T_ * 4);
  int*    eidx   = (int*)carve((size_t)T_ * 4);
  int*    tlist  = (int*)carve((size_t)T_ * 4);
  int*    counts = (int*)carve(64);
  int*    offs   = (int*)carve(64);
  int*    fill   = (int*)carve(64);

  embed_kernel<<<T_, 256, 0, stream>>>(x, tok_emb, pos_emb, h);

  for (int l = 0; l < L_; l++) {
    // ---- attention half
    ln_kernel<false, true><<<T_, 256, 0, stream>>>(h, ln1_w + l * D_, ln1_b + l * D_,
                                                   nullptr, x1b);
    conv_bf16_kernel<<<(3 * D_ * D_) / 1024, 256, 0, stream>>>(
        in_proj_w + (size_t)l * 3 * D_ * D_, wqb, 3 * D_ * D_);
    gemm_mfma<0><<<dim3(48, 16, 1), 256, 0, stream>>>(
        x1b, wqb, in_proj_b + (size_t)l * 3 * D_, nullptr, qkvb,
        nullptr, nullptr, nullptr, nullptr, 3 * D_, D_);
    attn_mfma_kernel<<<dim3(S_ / 64, B_ * NH_), 256, 0, stream>>>(qkvb, attnb);
    conv_bf16_kernel<<<(D_ * D_) / 1024, 256, 0, stream>>>(
        out_w + (size_t)l * D_ * D_, wob, D_ * D_);
    gemm_mfma<1><<<dim3(16, 16, 1), 256, 0, stream>>>(
        attnb, wob, out_b + (size_t)l * D_, h, nullptr,
        nullptr, nullptr, nullptr, nullptr, D_, D_);

    // ---- MoE half
    ln_kernel<true, true><<<T_, 256, 0, stream>>>(h, ln2_w + l * D_, ln2_b + l * D_,
                                                  x1, x1b);
    zero_counts_kernel<<<1, 64, 0, stream>>>(counts);
    route_kernel<<<T_, 64, 0, stream>>>(x1,
        gr_w + (size_t)l * D_ * G_, gr_b + (size_t)l * G_,
        er_w + (size_t)l * G_ * D_ * EPG_, er_b + (size_t)l * G_ * EPG_,
        eidx, gate, counts);
    scan_kernel<<<1, 1, 0, stream>>>(counts, offs, fill);
    scatter_kernel<<<T_ / 256, 256, 0, stream>>>(eidx, fill, tlist);

    // w1: [e][D,H] f32 -> [e][H,D] bf16
    transpose_conv_kernel<<<dim3(H_ / 64, D_ / 64, NE_), 256, 0, stream>>>(
        w1 + (size_t)l * NE_ * D_ * H_, wmb, D_, H_);
    gemm_mfma<2><<<dim3(H_ / 64, T_ / 128, NE_), 256, 0, stream>>>(
        x1b, wmb, b1 + (size_t)l * NE_ * H_, nullptr, hmidb,
        tlist, offs, counts, nullptr, H_, D_);
    // w2: [e][H,D] f32 -> [e][D,H] bf16
    transpose_conv_kernel<<<dim3(D_ / 64, H_ / 64, NE_), 256, 0, stream>>>(
        w2 + (size_t)l * NE_ * H_ * D_, wmb, H_, D_);
    gemm_mfma<3><<<dim3(D_ / 64, T_ / 128, NE_), 256, 0, stream>>>(
        hmidb, wmb, b2 + (size_t)l * NE_ * D_, h, nullptr,
        tlist, offs, counts, gate, D_, H_);
  }

  ln_kernel<true, false><<<T_, 256, 0, stream>>>(h, lnf_w, lnf_b, x1, nullptr);
  mean_part_kernel<<<dim3(B_ * D_ / 256, 16), 256, 0, stream>>>(x1, part);
  mean_final_kernel<<<B_ * D_ / 256, 256, 0, stream>>>(part, hm);
  head_kernel<<<NC_ / 4, 256, 0, stream>>>(hm, head_w, head_b, (float*)d_out);
}

// Round 3
// 1119.020 us; speedup vs baseline: 4.4247x; 1.3895x over previous
//
#include <hip/hip_runtime.h>
#include <hip/hip_bf16.h>
#include <cstdint>
#include <cstddef>

#define D_   1024
#define H_   2048
#define G_   4
#define EPG_ 2
#define NE_  8      // G*EPG
#define NH_  16
#define HD_  64
#define L_   4
#define V_   32000
#define NC_  32000
#define B_   2
#define S_   1024
#define T_   2048   // B*S

typedef __attribute__((__ext_vector_type__(8))) __bf16 bf16x8;
typedef __attribute__((__ext_vector_type__(4))) __bf16 bf16x4;
typedef __attribute__((__ext_vector_type__(4))) float  f32x4;

// async global->LDS, 16B per lane. Dest must be linear (wave base + lane*16).
__device__ __forceinline__ void gl_lds16(const void* g, void* l) {
  __builtin_amdgcn_global_load_lds(
      (const __attribute__((address_space(1))) void*)g,
      (__attribute__((address_space(3))) void*)l, 16, 0, 0);
}

// ---------------------------------------------------------------- embed
__global__ __launch_bounds__(256) void embed_kernel(const int* __restrict__ x,
    const float* __restrict__ tok, const float* __restrict__ pos,
    float* __restrict__ h) {
  int t = blockIdx.x;
  int tid = threadIdx.x;
  int token = x[t];
  int s = t & (S_ - 1);
  float4 tv = *(const float4*)(tok + (size_t)token * D_ + tid * 4);
  float4 pv = *(const float4*)(pos + (size_t)s * D_ + tid * 4);
  float4 r;
  r.x = tv.x + pv.x; r.y = tv.y + pv.y; r.z = tv.z + pv.z; r.w = tv.w + pv.w;
  *(float4*)(h + (size_t)t * D_ + tid * 4) = r;
}

// ---------------------------------------------------------------- layernorm
__device__ __forceinline__ float block_sum256(float v, float* sbuf) {
  #pragma unroll
  for (int o = 32; o >= 1; o >>= 1) v += __shfl_xor(v, o, 64);
  int tid = threadIdx.x;
  if ((tid & 63) == 0) sbuf[tid >> 6] = v;
  __syncthreads();
  float r = sbuf[0] + sbuf[1] + sbuf[2] + sbuf[3];
  __syncthreads();
  return r;
}

template<bool F32OUT, bool BFOUT>
__global__ __launch_bounds__(256) void ln_kernel(const float* __restrict__ X,
    const float* __restrict__ w, const float* __restrict__ b,
    float* __restrict__ Yf, __bf16* __restrict__ Yb) {
  __shared__ float sbuf[4];
  int t = blockIdx.x, tid = threadIdx.x;
  const float* xr = X + (size_t)t * D_;
  float4 v = *(const float4*)(xr + tid * 4);
  float sum = v.x + v.y + v.z + v.w;
  float m = block_sum256(sum, sbuf) * (1.0f / D_);
  float dx = v.x - m, dy = v.y - m, dz = v.z - m, dw = v.w - m;
  float vs = dx * dx + dy * dy + dz * dz + dw * dw;
  float var = block_sum256(vs, sbuf) * (1.0f / D_);
  float rs = rsqrtf(var + 1e-5f);
  float4 wv = *(const float4*)(w + tid * 4);
  float4 bv = *(const float4*)(b + tid * 4);
  float4 o;
  o.x = dx * rs * wv.x + bv.x;
  o.y = dy * rs * wv.y + bv.y;
  o.z = dz * rs * wv.z + bv.z;
  o.w = dw * rs * wv.w + bv.w;
  if (F32OUT) *(float4*)(Yf + (size_t)t * D_ + tid * 4) = o;
  if (BFOUT) {
    bf16x4 ob = {(__bf16)o.x, (__bf16)o.y, (__bf16)o.z, (__bf16)o.w};
    *(bf16x4*)(Yb + (size_t)t * D_ + tid * 4) = ob;
  }
}

// ---------------------------------------------------------------- fp32 -> bf16 flat convert
__global__ __launch_bounds__(256) void conv_bf16_kernel(const float* __restrict__ in,
    __bf16* __restrict__ out, int n) {
  int i = (blockIdx.x * 256 + threadIdx.x) * 4;
  if (i >= n) return;
  float4 v = *(const float4*)(in + i);
  bf16x4 o = {(__bf16)v.x, (__bf16)v.y, (__bf16)v.z, (__bf16)v.w};
  *(bf16x4*)(out + i) = o;
}

// ---------------------------------------------------------------- transpose + convert: per z, src [M,N] f32 -> dst [N,M] bf16
__global__ __launch_bounds__(256) void transpose_conv_kernel(const float* __restrict__ src,
    __bf16* __restrict__ dst, int M, int N) {
  __shared__ float tile[64][65];
  int e = blockIdx.z;
  src += (size_t)e * M * N;
  dst += (size_t)e * M * N;
  int r0 = blockIdx.y * 64;
  int c0 = blockIdx.x * 64;
  int tid = threadIdx.x;
  #pragma unroll
  for (int it = 0; it < 16; it++) {
    int idx = tid + it * 256;
    int r = idx >> 6, c = idx & 63;
    tile[r][c] = src[(size_t)(r0 + r) * N + c0 + c];
  }
  __syncthreads();
  #pragma unroll
  for (int it = 0; it < 16; it++) {
    int idx = tid + it * 256;
    int r = idx >> 6, c = idx & 63;
    dst[(size_t)(c0 + r) * M + r0 + c] = (__bf16)tile[c][r];
  }
}

// ---------------------------------------------------------------- bf16 MFMA GEMM (m97 structure)
// C[M,N] = A[M,K] @ W[N,K]^T + bias. Tile 128 x (NF*32). 4 waves in 2x2.
// LDS linear, XOR-swizzled 16B units (swizzle on global src + on ds_read).
// MODE 0: Cb = acc+bias (bf16)                [qkv]
// MODE 1: Cf += acc+bias (f32 residual)       [out-proj]
// MODE 2: gather rows; Cb = relu(acc+bias)    [moe w1]
// MODE 3: gather rows; Cf += gate*(acc+bias)  [moe w2]
template<int MODE, int NF>   // NF = 4 -> 128-col tile, NF = 2 -> 64-col tile
__global__ __launch_bounds__(256) void gemm_mfma(
    const __bf16* __restrict__ A, const __bf16* __restrict__ W,
    const float* __restrict__ bias, float* __restrict__ Cf,
    __bf16* __restrict__ Cb, const int* __restrict__ tlist,
    const int* __restrict__ offs, const int* __restrict__ counts,
    const float* __restrict__ gate, int N, int K) {
  __shared__ __bf16 As[128 * 64];        // [row][8 units of 8 bf16], units swizzled
  __shared__ __bf16 Bs[NF * 32 * 64];
  int e = blockIdx.z;
  int cnt = (MODE >= 2) ? counts[e] : T_;
  int row0 = blockIdx.y * 128;
  if (row0 >= cnt) return;
  int lbase = (MODE >= 2) ? offs[e] : 0;
  int col0 = blockIdx.x * (NF * 32);
  const __bf16* Wp = W + (size_t)e * N * K;
  const float* bp = bias + (size_t)e * N;
  int tid = threadIdx.x;
  int w = tid >> 6, lane = tid & 63, lq = lane & 15, lg = lane >> 4;
  int wr = w >> 1, wc = w & 1;

  // staging source pointers (inverse-swizzled 16B units)
  const __bf16* asrc[4];
  #pragma unroll
  for (int it = 0; it < 4; it++) {
    int v = it * 256 + tid;
    int r = v >> 3, u = v & 7;
    int gr = row0 + r;
    long rowidx;
    if (MODE >= 2) rowidx = tlist[lbase + ((gr < cnt) ? gr : cnt - 1)];
    else rowidx = gr;
    asrc[it] = A + (size_t)rowidx * K + (u ^ (r & 7)) * 8;
  }
  const __bf16* bsrc[NF];
  #pragma unroll
  for (int it = 0; it < NF; it++) {
    int v = it * 256 + tid;
    int n = v >> 3, u = v & 7;
    bsrc[it] = Wp + (size_t)(col0 + n) * K + (u ^ (n & 7)) * 8;
  }

  f32x4 acc[4][NF] = {};
  for (int k0 = 0; k0 < K; k0 += 64) {
    #pragma unroll
    for (int it = 0; it < 4; it++)
      gl_lds16(asrc[it] + k0, &As[(it * 256 + tid) * 8]);
    #pragma unroll
    for (int it = 0; it < NF; it++)
      gl_lds16(bsrc[it] + k0, &Bs[(it * 256 + tid) * 8]);
    __syncthreads();
    #pragma unroll
    for (int kk = 0; kk < 2; kk++) {
      bf16x8 a[4], b[NF];
      int us = ((lg + kk * 4) ^ (lq & 7)) * 8;
      #pragma unroll
      for (int fi = 0; fi < 4; fi++)
        a[fi] = *(const bf16x8*)&As[(wr * 64 + fi * 16 + lq) * 64 + us];
      #pragma unroll
      for (int fj = 0; fj < NF; fj++)
        b[fj] = *(const bf16x8*)&Bs[(wc * (NF * 16) + fj * 16 + lq) * 64 + us];
      #pragma unroll
      for (int fi = 0; fi < 4; fi++)
        #pragma unroll
        for (int fj = 0; fj < NF; fj++)
          acc[fi][fj] = __builtin_amdgcn_mfma_f32_16x16x32_bf16(a[fi], b[fj], acc[fi][fj], 0, 0, 0);
    }
    __syncthreads();
  }

  #pragma unroll
  for (int fi = 0; fi < 4; fi++) {
    #pragma unroll
    for (int v = 0; v < 4; v++) {
      int r = row0 + wr * 64 + fi * 16 + lg * 4 + v;
      long orow;
      float gv = 1.f;
      if (MODE >= 2) {
        if (r >= cnt) continue;
        orow = tlist[lbase + r];
        if (MODE == 3) gv = gate[orow];
      } else {
        orow = r;
      }
      #pragma unroll
      for (int fj = 0; fj < NF; fj++) {
        int c = col0 + wc * (NF * 16) + fj * 16 + lq;
        float val = acc[fi][fj][v] + bp[c];
        if (MODE == 0)      Cb[orow * N + c] = (__bf16)val;
        else if (MODE == 1) Cf[orow * N + c] += val;
        else if (MODE == 2) Cb[orow * N + c] = (__bf16)fmaxf(val, 0.f);
        else                Cf[orow * N + c] += gv * val;
      }
    }
  }
}

// ---------------------------------------------------------------- flash attention, bf16 MFMA
__global__ __launch_bounds__(256) void attn_mfma_kernel(const __bf16* __restrict__ qkv,
                                                        __bf16* __restrict__ out) {
  __shared__ __bf16 Ks[64][72];
  __shared__ __bf16 Vt[64][72];   // transposed: [d][kv]
  __shared__ __bf16 Ps[64][72];
  int tid = threadIdx.x;
  int w = tid >> 6, lane = tid & 63, lq = lane & 15, lg = lane >> 4;
  int qt = blockIdx.x, b = blockIdx.y >> 4, hh = blockIdx.y & 15;
  const __bf16* qbase = qkv + (size_t)b * S_ * 3 * D_ + hh * HD_;

  bf16x8 qa[2];
  {
    const __bf16* qp = qbase + (size_t)(qt * 64 + w * 16 + lq) * 3 * D_ + lg * 8;
    qa[0] = *(const bf16x8*)qp;
    qa[1] = *(const bf16x8*)(qp + 32);
  }

  f32x4 o[4] = {};
  float m_[4] = {-1e30f, -1e30f, -1e30f, -1e30f};
  float l_[4] = {0.f, 0.f, 0.f, 0.f};

  for (int kt = 0; kt <= qt; kt++) {
    #pragma unroll
    for (int it = 0; it < 2; it++) {
      int idx = tid + it * 256;
      int row = idx >> 3, c8 = idx & 7;
      const __bf16* kp = qbase + (size_t)(kt * 64 + row) * 3 * D_ + D_ + c8 * 8;
      *(bf16x8*)&Ks[row][c8 * 8] = *(const bf16x8*)kp;
      bf16x8 vv = *(const bf16x8*)(kp + D_);
      #pragma unroll
      for (int j = 0; j < 8; j++) Vt[c8 * 8 + j][row] = vv[j];
    }
    __syncthreads();

    f32x4 s[4] = {};
    #pragma unroll
    for (int kk = 0; kk < 2; kk++)
      #pragma unroll
      for (int fc = 0; fc < 4; fc++) {
        bf16x8 kf = *(const bf16x8*)&Ks[fc * 16 + lq][lg * 8 + kk * 32];
        s[fc] = __builtin_amdgcn_mfma_f32_16x16x32_bf16(qa[kk], kf, s[fc], 0, 0, 0);
      }

    #pragma unroll
    for (int fc = 0; fc < 4; fc++)
      #pragma unroll
      for (int v = 0; v < 4; v++) {
        float sv = s[fc][v] * 0.125f;
        if (kt == qt && (fc * 16 + lq) > (w * 16 + lg * 4 + v)) sv = -1e30f;
        s[fc][v] = sv;
      }

    float corr[4];
    #pragma unroll
    for (int v = 0; v < 4; v++) {
      float rm = fmaxf(fmaxf(s[0][v], s[1][v]), fmaxf(s[2][v], s[3][v]));
      #pragma unroll
      for (int o2 = 8; o2 >= 1; o2 >>= 1) rm = fmaxf(rm, __shfl_xor(rm, o2, 64));
      float mnew = fmaxf(m_[v], rm);
      float cc = __expf(m_[v] - mnew);
      float rs = 0.f;
      #pragma unroll
      for (int fc = 0; fc < 4; fc++) {
        float p = __expf(s[fc][v] - mnew);
        s[fc][v] = p; rs += p;
      }
      #pragma unroll
      for (int o2 = 8; o2 >= 1; o2 >>= 1) rs += __shfl_xor(rs, o2, 64);
      l_[v] = l_[v] * cc + rs;
      m_[v] = mnew;
      corr[v] = cc;
    }
    #pragma unroll
    for (int dc = 0; dc < 4; dc++)
      #pragma unroll
      for (int v = 0; v < 4; v++) o[dc][v] *= corr[v];

    #pragma unroll
    for (int fc = 0; fc < 4; fc++)
      #pragma unroll
      for (int v = 0; v < 4; v++)
        Ps[w * 16 + lg * 4 + v][fc * 16 + lq] = (__bf16)s[fc][v];
    __syncthreads();

    #pragma unroll
    for (int kk = 0; kk < 2; kk++) {
      bf16x8 pa = *(const bf16x8*)&Ps[w * 16 + lq][lg * 8 + kk * 32];
      #pragma unroll
      for (int dc = 0; dc < 4; dc++) {
        bf16x8 vb = *(const bf16x8*)&Vt[dc * 16 + lq][lg * 8 + kk * 32];
        o[dc] = __builtin_amdgcn_mfma_f32_16x16x32_bf16(pa, vb, o[dc], 0, 0, 0);
      }
    }
    __syncthreads();
  }

  #pragma unroll
  for (int v = 0; v < 4; v++) {
    float inv = 1.0f / l_[v];
    int row = qt * 64 + w * 16 + lg * 4 + v;
    __bf16* op = out + ((size_t)b * S_ + row) * D_ + hh * HD_;
    #pragma unroll
    for (int dc = 0; dc < 4; dc++)
      op[dc * 16 + lq] = (__bf16)(o[dc][v] * inv);
  }
}

// ---------------------------------------------------------------- routing (1 wave / token)
__global__ __launch_bounds__(64) void route_kernel(const float* __restrict__ X,
    const float* __restrict__ gw, const float* __restrict__ gb,
    const float* __restrict__ ew, const float* __restrict__ eb,
    int* __restrict__ eidx, float* __restrict__ gate) {
  int t = blockIdx.x;
  int lane = threadIdx.x;
  const float* xr = X + (size_t)t * D_;
  float g0 = 0, g1 = 0, g2 = 0, g3 = 0;
  #pragma unroll
  for (int k = 0; k < 16; k++) {
    int d = lane + 64 * k;
    float xv = xr[d];
    float4 gv = *(const float4*)(gw + (size_t)d * G_);
    g0 += xv * gv.x; g1 += xv * gv.y; g2 += xv * gv.z; g3 += xv * gv.w;
  }
  #pragma unroll
  for (int o = 32; o >= 1; o >>= 1) {
    g0 += __shfl_xor(g0, o, 64); g1 += __shfl_xor(g1, o, 64);
    g2 += __shfl_xor(g2, o, 64); g3 += __shfl_xor(g3, o, 64);
  }
  g0 += gb[0]; g1 += gb[1]; g2 += gb[2]; g3 += gb[3];
  float mx = fmaxf(fmaxf(g0, g1), fmaxf(g2, g3));
  float p0 = __expf(g0 - mx), p1 = __expf(g1 - mx), p2 = __expf(g2 - mx), p3 = __expf(g3 - mx);
  float psum = p0 + p1 + p2 + p3;
  int gidx = 0; float best = g0;
  if (g1 > best) { best = g1; gidx = 1; }
  if (g2 > best) { best = g2; gidx = 2; }
  if (g3 > best) { best = g3; gidx = 3; }
  float gpsel = ((gidx == 0) ? p0 : (gidx == 1) ? p1 : (gidx == 2) ? p2 : p3) / psum;

  const float* ewg = ew + (size_t)gidx * D_ * EPG_;
  float e0 = 0, e1 = 0;
  #pragma unroll
  for (int k = 0; k < 16; k++) {
    int d = lane + 64 * k;
    float xv = xr[d];
    float2 ev = *(const float2*)(ewg + (size_t)d * EPG_);
    e0 += xv * ev.x; e1 += xv * ev.y;
  }
  #pragma unroll
  for (int o = 32; o >= 1; o >>= 1) {
    e0 += __shfl_xor(e0, o, 64); e1 += __shfl_xor(e1, o, 64);
  }
  e0 += eb[gidx * EPG_ + 0]; e1 += eb[gidx * EPG_ + 1];
  float em = fmaxf(e0, e1);
  float q0 = __expf(e0 - em), q1 = __expf(e1 - em);
  int ei = (e1 > e0) ? 1 : 0;
  float epsel = ((ei == 0) ? q0 : q1) / (q0 + q1);
  if (lane == 0) {
    eidx[t] = gidx * EPG_ + ei;
    gate[t] = gpsel * epsel;
  }
}

// ---------------------------------------------------------------- finalize: histogram + scan + stable scatter (1 block)
__global__ __launch_bounds__(256) void finalize_kernel(const int* __restrict__ eidx,
    int* __restrict__ counts, int* __restrict__ offs, int* __restrict__ tlist) {
  __shared__ int hist[256][NE_];
  __shared__ int eoff[NE_];
  int tid = threadIdx.x;
  int loc[NE_];
  #pragma unroll
  for (int e = 0; e < NE_; e++) loc[e] = 0;
  int te[8];
  #pragma unroll
  for (int i = 0; i < 8; i++) { te[i] = eidx[tid * 8 + i]; loc[te[i]]++; }
  #pragma unroll
  for (int e = 0; e < NE_; e++) hist[tid][e] = loc[e];
  __syncthreads();
  for (int off = 1; off < 256; off <<= 1) {
    int v[NE_];
    #pragma unroll
    for (int e = 0; e < NE_; e++) v[e] = (tid >= off) ? hist[tid - off][e] : 0;
    __syncthreads();
    #pragma unroll
    for (int e = 0; e < NE_; e++) hist[tid][e] += v[e];
    __syncthreads();
  }
  if (tid == 0) {
    int acc = 0;
    for (int e = 0; e < NE_; e++) {
      int c = hist[255][e];
      eoff[e] = acc; counts[e] = c; offs[e] = acc; acc += c;
    }
  }
  __syncthreads();
  int run[NE_];
  #pragma unroll
  for (int e = 0; e < NE_; e++) run[e] = eoff[e] + hist[tid][e] - loc[e];
  #pragma unroll
  for (int i = 0; i < 8; i++) {
    int e = te[i];
    tlist[run[e]++] = tid * 8 + i;
  }
}

// ---------------------------------------------------------------- final mean + head (fp32)
__global__ __launch_bounds__(256) void mean_part_kernel(const float* __restrict__ X,
                                                        float* __restrict__ part) {
  int bd = blockIdx.x * 256 + threadIdx.x;
  int chunk = blockIdx.y;
  int b = bd >> 10, d = bd & 1023;
  float s = 0.f;
  #pragma unroll 4
  for (int i = 0; i < 64; i++) {
    int sidx = chunk * 64 + i;
    s += X[((size_t)b * S_ + sidx) * D_ + d];
  }
  part[chunk * T_ + bd] = s;
}

__global__ __launch_bounds__(256) void mean_final_kernel(const float* __restrict__ part,
                                                         float* __restrict__ hm) {
  int bd = blockIdx.x * 256 + threadIdx.x;
  float s = 0.f;
  #pragma unroll
  for (int c = 0; c < 16; c++) s += part[c * T_ + bd];
  hm[bd] = s * (1.0f / S_);
}

__global__ __launch_bounds__(256) void head_kernel(const float* __restrict__ hm,
    const float* __restrict__ hw, const float* __restrict__ hb,
    float* __restrict__ out) {
  int w = threadIdx.x >> 6;
  int lane = threadIdx.x & 63;
  int c = blockIdx.x * 4 + w;
  const float* row = hw + (size_t)c * D_;
  float acc0 = 0.f, acc1 = 0.f;
  #pragma unroll
  for (int k = 0; k < 4; k++) {
    int d = lane * 4 + k * 256;
    float4 wv = *(const float4*)(row + d);
    float4 h0 = *(const float4*)(hm + d);
    float4 h1 = *(const float4*)(hm + D_ + d);
    acc0 += wv.x * h0.x + wv.y * h0.y + wv.z * h0.z + wv.w * h0.w;
    acc1 += wv.x * h1.x + wv.y * h1.y + wv.z * h1.z + wv.w * h1.w;
  }
  #pragma unroll
  for (int o = 32; o >= 1; o >>= 1) {
    acc0 += __shfl_xor(acc0, o, 64);
    acc1 += __shfl_xor(acc1, o, 64);
  }
  if (lane == 0) {
    float bias = hb[c];
    out[c] = acc0 + bias;
    out[NC_ + c] = acc1 + bias;
  }
}

// ---------------------------------------------------------------- host launch
extern "C" void kernel_launch(void* const* d_in, const int* in_sizes, int n_in,
                              void* d_out, int out_size, void* d_ws, size_t ws_size,
                              hipStream_t stream) {
  const int*   x        = (const int*)d_in[0];
  const float* tok_emb  = (const float*)d_in[1];
  const float* pos_emb  = (const float*)d_in[2];
  const float* in_proj_w= (const float*)d_in[3];
  const float* in_proj_b= (const float*)d_in[4];
  const float* out_w    = (const float*)d_in[5];
  const float* out_b    = (const float*)d_in[6];
  const float* ln1_w    = (const float*)d_in[7];
  const float* ln1_b    = (const float*)d_in[8];
  const float* ln2_w    = (const float*)d_in[9];
  const float* ln2_b    = (const float*)d_in[10];
  const float* gr_w     = (const float*)d_in[11];
  const float* gr_b     = (const float*)d_in[12];
  const float* er_w     = (const float*)d_in[13];
  const float* er_b     = (const float*)d_in[14];
  const float* w1       = (const float*)d_in[15];
  const float* b1       = (const float*)d_in[16];
  const float* w2       = (const float*)d_in[17];
  const float* b2       = (const float*)d_in[18];
  const float* lnf_w    = (const float*)d_in[19];
  const float* lnf_b    = (const float*)d_in[20];
  const float* head_w   = (const float*)d_in[21];
  const float* head_b   = (const float*)d_in[22];

  char* wp = (char*)d_ws;
  auto carve = [&](size_t bytes) -> char* {
    char* p = wp;
    wp += (bytes + 255) & ~(size_t)255;
    return p;
  };
  float*  h      = (float*)carve((size_t)T_ * D_ * 4);
  float*  x1     = (float*)carve((size_t)T_ * D_ * 4);
  __bf16* x1b    = (__bf16*)carve((size_t)T_ * D_ * 2);
  __bf16* qkvb   = (__bf16*)carve((size_t)T_ * 3 * D_ * 2);
  __bf16* attnb  = (__bf16*)carve((size_t)T_ * D_ * 2);
  __bf16* hmidb  = (__bf16*)carve((size_t)T_ * H_ * 2);
  __bf16* wqb    = (__bf16*)carve((size_t)L_ * 3 * D_ * D_ * 2);
  __bf16* wob    = (__bf16*)carve((size_t)L_ * D_ * D_ * 2);
  __bf16* w1b    = (__bf16*)carve((size_t)L_ * NE_ * D_ * H_ * 2);
  __bf16* w2b    = (__bf16*)carve((size_t)L_ * NE_ * H_ * D_ * 2);
  float*  part   = (float*)carve((size_t)16 * T_ * 4);
  float*  hm     = (float*)carve((size_t)B_ * D_ * 4);
  float*  gate   = (float*)carve((size_t)T_ * 4);
  int*    eidx   = (int*)carve((size_t)T_ * 4);
  int*    tlist  = (int*)carve((size_t)T_ * 4);
  int*    counts = (int*)carve(64);
  int*    offs   = (int*)carve(64);

  // ---- upfront weight preparation (all layers)
  embed_kernel<<<T_, 256, 0, stream>>>(x, tok_emb, pos_emb, h);
  conv_bf16_kernel<<<(L_ * 3 * D_ * D_) / 1024, 256, 0, stream>>>(in_proj_w, wqb, L_ * 3 * D_ * D_);
  conv_bf16_kernel<<<(L_ * D_ * D_) / 1024, 256, 0, stream>>>(out_w, wob, L_ * D_ * D_);
  // w1: [l,e][D,H] -> [l,e][H,D] bf16 ; w2: [l,e][H,D] -> [l,e][D,H] bf16
  transpose_conv_kernel<<<dim3(H_ / 64, D_ / 64, L_ * NE_), 256, 0, stream>>>(w1, w1b, D_, H_);
  transpose_conv_kernel<<<dim3(D_ / 64, H_ / 64, L_ * NE_), 256, 0, stream>>>(w2, w2b, H_, D_);

  for (int l = 0; l < L_; l++) {
    // ---- attention half
    ln_kernel<false, true><<<T_, 256, 0, stream>>>(h, ln1_w + l * D_, ln1_b + l * D_,
                                                   nullptr, x1b);
    gemm_mfma<0, 4><<<dim3(24, 16, 1), 256, 0, stream>>>(
        x1b, wqb + (size_t)l * 3 * D_ * D_, in_proj_b + (size_t)l * 3 * D_, nullptr, qkvb,
        nullptr, nullptr, nullptr, nullptr, 3 * D_, D_);
    attn_mfma_kernel<<<dim3(S_ / 64, B_ * NH_), 256, 0, stream>>>(qkvb, attnb);
    gemm_mfma<1, 2><<<dim3(16, 16, 1), 256, 0, stream>>>(
        attnb, wob + (size_t)l * D_ * D_, out_b + (size_t)l * D_, h, nullptr,
        nullptr, nullptr, nullptr, nullptr, D_, D_);

    // ---- MoE half
    ln_kernel<true, true><<<T_, 256, 0, stream>>>(h, ln2_w + l * D_, ln2_b + l * D_,
                                                  x1, x1b);
    route_kernel<<<T_, 64, 0, stream>>>(x1,
        gr_w + (size_t)l * D_ * G_, gr_b + (size_t)l * G_,
        er_w + (size_t)l * G_ * D_ * EPG_, er_b + (size_t)l * G_ * EPG_,
        eidx, gate);
    finalize_kernel<<<1, 256, 0, stream>>>(eidx, counts, offs, tlist);

    gemm_mfma<2, 4><<<dim3(H_ / 128, T_ / 128, NE_), 256, 0, stream>>>(
        x1b, w1b + (size_t)l * NE_ * D_ * H_, b1 + (size_t)l * NE_ * H_, nullptr, hmidb,
        tlist, offs, counts, nullptr, H_, D_);
    gemm_mfma<3, 2><<<dim3(D_ / 64, T_ / 128, NE_), 256, 0, stream>>>(
        hmidb, w2b + (size_t)l * NE_ * H_ * D_, b2 + (size_t)l * NE_ * D_, h, nullptr,
        tlist, offs, counts, gate, D_, H_);
  }

  ln_kernel<true, false><<<T_, 256, 0, stream>>>(h, lnf_w, lnf_b, x1, nullptr);
  mean_part_kernel<<<dim3(B_ * D_ / 256, 16), 256, 0, stream>>>(x1, part);
  mean_final_kernel<<<B_ * D_ / 256, 256, 0, stream>>>(part, hm);
  head_kernel<<<NC_ / 4, 256, 0, stream>>>(hm, head_w, head_b, (float*)d_out);
}

// Round 4
// 1036.761 us; speedup vs baseline: 4.7757x; 1.0793x over previous
//
#include <hip/hip_runtime.h>
#include <hip/hip_bf16.h>
#include <cstdint>
#include <cstddef>

#define D_   1024
#define H_   2048
#define G_   4
#define EPG_ 2
#define NE_  8      // G*EPG
#define NH_  16
#define HD_  64
#define L_   4
#define V_   32000
#define NC_  32000
#define B_   2
#define S_   1024
#define T_   2048   // B*S

typedef __attribute__((__ext_vector_type__(8))) __bf16 bf16x8;
typedef __attribute__((__ext_vector_type__(4))) __bf16 bf16x4;
typedef __attribute__((__ext_vector_type__(4))) float  f32x4;

// async global->LDS, 16B per lane. Dest must be linear (wave base + lane*16).
__device__ __forceinline__ void gl_lds16(const void* g, void* l) {
  __builtin_amdgcn_global_load_lds(
      (const __attribute__((address_space(1))) void*)g,
      (__attribute__((address_space(3))) void*)l, 16, 0, 0);
}

// ---------------------------------------------------------------- embed
__global__ __launch_bounds__(256) void embed_kernel(const int* __restrict__ x,
    const float* __restrict__ tok, const float* __restrict__ pos,
    float* __restrict__ h) {
  int t = blockIdx.x;
  int tid = threadIdx.x;
  int token = x[t];
  int s = t & (S_ - 1);
  float4 tv = *(const float4*)(tok + (size_t)token * D_ + tid * 4);
  float4 pv = *(const float4*)(pos + (size_t)s * D_ + tid * 4);
  float4 r;
  r.x = tv.x + pv.x; r.y = tv.y + pv.y; r.z = tv.z + pv.z; r.w = tv.w + pv.w;
  *(float4*)(h + (size_t)t * D_ + tid * 4) = r;
}

// ---------------------------------------------------------------- layernorm
__device__ __forceinline__ float block_sum256(float v, float* sbuf) {
  #pragma unroll
  for (int o = 32; o >= 1; o >>= 1) v += __shfl_xor(v, o, 64);
  int tid = threadIdx.x;
  if ((tid & 63) == 0) sbuf[tid >> 6] = v;
  __syncthreads();
  float r = sbuf[0] + sbuf[1] + sbuf[2] + sbuf[3];
  __syncthreads();
  return r;
}

template<bool F32OUT, bool BFOUT>
__global__ __launch_bounds__(256) void ln_kernel(const float* __restrict__ X,
    const float* __restrict__ w, const float* __restrict__ b,
    float* __restrict__ Yf, __bf16* __restrict__ Yb) {
  __shared__ float sbuf[4];
  int t = blockIdx.x, tid = threadIdx.x;
  const float* xr = X + (size_t)t * D_;
  float4 v = *(const float4*)(xr + tid * 4);
  float sum = v.x + v.y + v.z + v.w;
  float m = block_sum256(sum, sbuf) * (1.0f / D_);
  float dx = v.x - m, dy = v.y - m, dz = v.z - m, dw = v.w - m;
  float vs = dx * dx + dy * dy + dz * dz + dw * dw;
  float var = block_sum256(vs, sbuf) * (1.0f / D_);
  float rs = rsqrtf(var + 1e-5f);
  float4 wv = *(const float4*)(w + tid * 4);
  float4 bv = *(const float4*)(b + tid * 4);
  float4 o;
  o.x = dx * rs * wv.x + bv.x;
  o.y = dy * rs * wv.y + bv.y;
  o.z = dz * rs * wv.z + bv.z;
  o.w = dw * rs * wv.w + bv.w;
  if (F32OUT) *(float4*)(Yf + (size_t)t * D_ + tid * 4) = o;
  if (BFOUT) {
    bf16x4 ob = {(__bf16)o.x, (__bf16)o.y, (__bf16)o.z, (__bf16)o.w};
    *(bf16x4*)(Yb + (size_t)t * D_ + tid * 4) = ob;
  }
}

// ---------------------------------------------------------------- bf16 MFMA GEMM
// C[M,N] = A[M,K] @ Wmat + bias, A bf16, W f32 (converted at stage time).
// KN=false: W stored [N,K] (row n k-contiguous);  KN=true: W stored [K,N].
// Tile 128 x (NF*32). 4 waves 2x2. A via global_load_lds (pre-swizzled src);
// B reg-staged f32->bf16 with swizzled ds_write (same XOR layout as reads).
// MODE 0: Cb = acc+bias (bf16)                [qkv]
// MODE 1: Cf += acc+bias (f32 residual)       [out-proj]
// MODE 2: gather rows; Cb = relu(acc+bias)    [moe w1]
// MODE 3: gather rows; Cf += gate*(acc+bias)  [moe w2]
template<int MODE, int NF, bool KN>
__global__ __launch_bounds__(256) void gemm_mfma(
    const __bf16* __restrict__ A, const float* __restrict__ W,
    const float* __restrict__ bias, float* __restrict__ Cf,
    __bf16* __restrict__ Cb, const int* __restrict__ tlist,
    const int* __restrict__ offs, const int* __restrict__ counts,
    const float* __restrict__ gate, int N, int K) {
  __shared__ __bf16 As[128 * 64];        // [row][8 units of 8 bf16], units swizzled
  __shared__ __bf16 Bs[NF * 32 * 64];
  int e = blockIdx.z;
  int cnt = (MODE >= 2) ? counts[e] : T_;
  int row0 = blockIdx.y * 128;
  if (row0 >= cnt) return;
  int lbase = (MODE >= 2) ? offs[e] : 0;
  int col0 = blockIdx.x * (NF * 32);
  const float* Wp = W + (size_t)e * N * K;
  const float* bp = bias + (size_t)e * N;
  int tid = threadIdx.x;
  int w = tid >> 6, lane = tid & 63, lq = lane & 15, lg = lane >> 4;
  int wr = w >> 1, wc = w & 1;

  // A staging source pointers (inverse-swizzled 16B units)
  const __bf16* asrc[4];
  #pragma unroll
  for (int it = 0; it < 4; it++) {
    int v = it * 256 + tid;
    int r = v >> 3, u = v & 7;
    int gr = row0 + r;
    long rowidx;
    if (MODE >= 2) rowidx = tlist[lbase + ((gr < cnt) ? gr : cnt - 1)];
    else rowidx = gr;
    asrc[it] = A + (size_t)rowidx * K + (u ^ (r & 7)) * 8;
  }
  // B staging descriptors
  const float* bsrc[NF];
  int bdst[NF];
  #pragma unroll
  for (int it = 0; it < NF; it++) {
    if (!KN) {
      int v = it * 256 + tid;
      int n = v >> 3, u = v & 7;
      bsrc[it] = Wp + (size_t)(col0 + n) * K + u * 8;
      bdst[it] = n * 64 + (u ^ (n & 7)) * 8;
    } else {
      int v = it * 256 + tid;
      int n = v & (NF * 32 - 1), u = v / (NF * 32);
      bsrc[it] = Wp + (size_t)(u * 8) * N + col0 + n;
      bdst[it] = n * 64 + (u ^ (n & 7)) * 8;
    }
  }

  f32x4 acc[4][NF] = {};
  for (int k0 = 0; k0 < K; k0 += 64) {
    #pragma unroll
    for (int it = 0; it < 4; it++)
      gl_lds16(asrc[it] + k0, &As[(it * 256 + tid) * 8]);
    #pragma unroll
    for (int it = 0; it < NF; it++) {
      float f[8];
      if (!KN) {
        float4 f0 = *(const float4*)(bsrc[it] + k0);
        float4 f1 = *(const float4*)(bsrc[it] + k0 + 4);
        f[0] = f0.x; f[1] = f0.y; f[2] = f0.z; f[3] = f0.w;
        f[4] = f1.x; f[5] = f1.y; f[6] = f1.z; f[7] = f1.w;
      } else {
        #pragma unroll
        for (int j = 0; j < 8; j++)
          f[j] = bsrc[it][(size_t)(k0 + j) * N];
      }
      bf16x8 bb = {(__bf16)f[0], (__bf16)f[1], (__bf16)f[2], (__bf16)f[3],
                   (__bf16)f[4], (__bf16)f[5], (__bf16)f[6], (__bf16)f[7]};
      *(bf16x8*)&Bs[bdst[it]] = bb;
    }
    __syncthreads();
    #pragma unroll
    for (int kk = 0; kk < 2; kk++) {
      bf16x8 a[4], b[NF];
      int us = ((lg + kk * 4) ^ (lq & 7)) * 8;
      #pragma unroll
      for (int fi = 0; fi < 4; fi++)
        a[fi] = *(const bf16x8*)&As[(wr * 64 + fi * 16 + lq) * 64 + us];
      #pragma unroll
      for (int fj = 0; fj < NF; fj++)
        b[fj] = *(const bf16x8*)&Bs[(wc * (NF * 16) + fj * 16 + lq) * 64 + us];
      #pragma unroll
      for (int fi = 0; fi < 4; fi++)
        #pragma unroll
        for (int fj = 0; fj < NF; fj++)
          acc[fi][fj] = __builtin_amdgcn_mfma_f32_16x16x32_bf16(a[fi], b[fj], acc[fi][fj], 0, 0, 0);
    }
    __syncthreads();
  }

  #pragma unroll
  for (int fi = 0; fi < 4; fi++) {
    #pragma unroll
    for (int v = 0; v < 4; v++) {
      int r = row0 + wr * 64 + fi * 16 + lg * 4 + v;
      long orow;
      float gv = 1.f;
      if (MODE >= 2) {
        if (r >= cnt) continue;
        orow = tlist[lbase + r];
        if (MODE == 3) gv = gate[orow];
      } else {
        orow = r;
      }
      #pragma unroll
      for (int fj = 0; fj < NF; fj++) {
        int c = col0 + wc * (NF * 16) + fj * 16 + lq;
        float val = acc[fi][fj][v] + bp[c];
        if (MODE == 0)      Cb[orow * N + c] = (__bf16)val;
        else if (MODE == 1) Cf[orow * N + c] += val;
        else if (MODE == 2) Cb[orow * N + c] = (__bf16)fmaxf(val, 0.f);
        else                Cf[orow * N + c] += gv * val;
      }
    }
  }
}

// ---------------------------------------------------------------- flash attention, bf16 MFMA
// exp in base-2 domain (scale folded); per-lane deferred l-sum.
#define SC_LOG2 0.18033688011112042f   // (1/sqrt(64)) * log2(e)
__global__ __launch_bounds__(256) void attn_mfma_kernel(const __bf16* __restrict__ qkv,
                                                        __bf16* __restrict__ out) {
  __shared__ __bf16 Ks[64][72];
  __shared__ __bf16 Vt[64][72];   // transposed: [d][kv]
  __shared__ __bf16 Ps[64][72];
  int tid = threadIdx.x;
  int w = tid >> 6, lane = tid & 63, lq = lane & 15, lg = lane >> 4;
  int qt = blockIdx.x, b = blockIdx.y >> 4, hh = blockIdx.y & 15;
  const __bf16* qbase = qkv + (size_t)b * S_ * 3 * D_ + hh * HD_;

  bf16x8 qa[2];
  {
    const __bf16* qp = qbase + (size_t)(qt * 64 + w * 16 + lq) * 3 * D_ + lg * 8;
    qa[0] = *(const bf16x8*)qp;
    qa[1] = *(const bf16x8*)(qp + 32);
  }

  f32x4 o[4] = {};
  float m_[4] = {-1e30f, -1e30f, -1e30f, -1e30f};
  float l_[4] = {0.f, 0.f, 0.f, 0.f};   // per-lane partial row sums

  for (int kt = 0; kt <= qt; kt++) {
    #pragma unroll
    for (int it = 0; it < 2; it++) {
      int idx = tid + it * 256;
      int row = idx >> 3, c8 = idx & 7;
      const __bf16* kp = qbase + (size_t)(kt * 64 + row) * 3 * D_ + D_ + c8 * 8;
      *(bf16x8*)&Ks[row][c8 * 8] = *(const bf16x8*)kp;
      bf16x8 vv = *(const bf16x8*)(kp + D_);
      #pragma unroll
      for (int j = 0; j < 8; j++) Vt[c8 * 8 + j][row] = vv[j];
    }
    __syncthreads();

    f32x4 s[4] = {};
    #pragma unroll
    for (int kk = 0; kk < 2; kk++)
      #pragma unroll
      for (int fc = 0; fc < 4; fc++) {
        bf16x8 kf = *(const bf16x8*)&Ks[fc * 16 + lq][lg * 8 + kk * 32];
        s[fc] = __builtin_amdgcn_mfma_f32_16x16x32_bf16(qa[kk], kf, s[fc], 0, 0, 0);
      }

    // scale into log2 domain + causal mask
    #pragma unroll
    for (int fc = 0; fc < 4; fc++)
      #pragma unroll
      for (int v = 0; v < 4; v++) {
        float sv = s[fc][v] * SC_LOG2;
        if (kt == qt && (fc * 16 + lq) > (w * 16 + lg * 4 + v)) sv = -1e30f;
        s[fc][v] = sv;
      }

    float corr[4];
    #pragma unroll
    for (int v = 0; v < 4; v++) {
      float rm = fmaxf(fmaxf(s[0][v], s[1][v]), fmaxf(s[2][v], s[3][v]));
      #pragma unroll
      for (int o2 = 8; o2 >= 1; o2 >>= 1) rm = fmaxf(rm, __shfl_xor(rm, o2, 64));
      float mnew = fmaxf(m_[v], rm);
      float cc = exp2f(m_[v] - mnew);
      float rs = 0.f;
      #pragma unroll
      for (int fc = 0; fc < 4; fc++) {
        float p = exp2f(s[fc][v] - mnew);
        s[fc][v] = p; rs += p;
      }
      l_[v] = l_[v] * cc + rs;   // per-lane partial; reduce at end
      m_[v] = mnew;
      corr[v] = cc;
    }
    #pragma unroll
    for (int dc = 0; dc < 4; dc++)
      #pragma unroll
      for (int v = 0; v < 4; v++) o[dc][v] *= corr[v];

    #pragma unroll
    for (int fc = 0; fc < 4; fc++)
      #pragma unroll
      for (int v = 0; v < 4; v++)
        Ps[w * 16 + lg * 4 + v][fc * 16 + lq] = (__bf16)s[fc][v];
    __syncthreads();

    #pragma unroll
    for (int kk = 0; kk < 2; kk++) {
      bf16x8 pa = *(const bf16x8*)&Ps[w * 16 + lq][lg * 8 + kk * 32];
      #pragma unroll
      for (int dc = 0; dc < 4; dc++) {
        bf16x8 vb = *(const bf16x8*)&Vt[dc * 16 + lq][lg * 8 + kk * 32];
        o[dc] = __builtin_amdgcn_mfma_f32_16x16x32_bf16(pa, vb, o[dc], 0, 0, 0);
      }
    }
    __syncthreads();
  }

  // final row-sum reduction (deferred) + write
  #pragma unroll
  for (int v = 0; v < 4; v++) {
    float ls = l_[v];
    #pragma unroll
    for (int o2 = 8; o2 >= 1; o2 >>= 1) ls += __shfl_xor(ls, o2, 64);
    float inv = 1.0f / ls;
    int row = qt * 64 + w * 16 + lg * 4 + v;
    __bf16* op = out + ((size_t)b * S_ + row) * D_ + hh * HD_;
    #pragma unroll
    for (int dc = 0; dc < 4; dc++)
      op[dc * 16 + lq] = (__bf16)(o[dc][v] * inv);
  }
}

// ---------------------------------------------------------------- routing (1 wave / token)
__global__ __launch_bounds__(64) void route_kernel(const float* __restrict__ X,
    const float* __restrict__ gw, const float* __restrict__ gb,
    const float* __restrict__ ew, const float* __restrict__ eb,
    int* __restrict__ eidx, float* __restrict__ gate) {
  int t = blockIdx.x;
  int lane = threadIdx.x;
  const float* xr = X + (size_t)t * D_;
  float g0 = 0, g1 = 0, g2 = 0, g3 = 0;
  #pragma unroll
  for (int k = 0; k < 16; k++) {
    int d = lane + 64 * k;
    float xv = xr[d];
    float4 gv = *(const float4*)(gw + (size_t)d * G_);
    g0 += xv * gv.x; g1 += xv * gv.y; g2 += xv * gv.z; g3 += xv * gv.w;
  }
  #pragma unroll
  for (int o = 32; o >= 1; o >>= 1) {
    g0 += __shfl_xor(g0, o, 64); g1 += __shfl_xor(g1, o, 64);
    g2 += __shfl_xor(g2, o, 64); g3 += __shfl_xor(g3, o, 64);
  }
  g0 += gb[0]; g1 += gb[1]; g2 += gb[2]; g3 += gb[3];
  float mx = fmaxf(fmaxf(g0, g1), fmaxf(g2, g3));
  float p0 = __expf(g0 - mx), p1 = __expf(g1 - mx), p2 = __expf(g2 - mx), p3 = __expf(g3 - mx);
  float psum = p0 + p1 + p2 + p3;
  int gidx = 0; float best = g0;
  if (g1 > best) { best = g1; gidx = 1; }
  if (g2 > best) { best = g2; gidx = 2; }
  if (g3 > best) { best = g3; gidx = 3; }
  float gpsel = ((gidx == 0) ? p0 : (gidx == 1) ? p1 : (gidx == 2) ? p2 : p3) / psum;

  const float* ewg = ew + (size_t)gidx * D_ * EPG_;
  float e0 = 0, e1 = 0;
  #pragma unroll
  for (int k = 0; k < 16; k++) {
    int d = lane + 64 * k;
    float xv = xr[d];
    float2 ev = *(const float2*)(ewg + (size_t)d * EPG_);
    e0 += xv * ev.x; e1 += xv * ev.y;
  }
  #pragma unroll
  for (int o = 32; o >= 1; o >>= 1) {
    e0 += __shfl_xor(e0, o, 64); e1 += __shfl_xor(e1, o, 64);
  }
  e0 += eb[gidx * EPG_ + 0]; e1 += eb[gidx * EPG_ + 1];
  float em = fmaxf(e0, e1);
  float q0 = __expf(e0 - em), q1 = __expf(e1 - em);
  int ei = (e1 > e0) ? 1 : 0;
  float epsel = ((ei == 0) ? q0 : q1) / (q0 + q1);
  if (lane == 0) {
    eidx[t] = gidx * EPG_ + ei;
    gate[t] = gpsel * epsel;
  }
}

// ---------------------------------------------------------------- finalize: histogram + scan + stable scatter (1 block)
__global__ __launch_bounds__(256) void finalize_kernel(const int* __restrict__ eidx,
    int* __restrict__ counts, int* __restrict__ offs, int* __restrict__ tlist) {
  __shared__ int hist[256][NE_];
  __shared__ int eoff[NE_];
  int tid = threadIdx.x;
  int loc[NE_];
  #pragma unroll
  for (int e = 0; e < NE_; e++) loc[e] = 0;
  int te[8];
  #pragma unroll
  for (int i = 0; i < 8; i++) { te[i] = eidx[tid * 8 + i]; loc[te[i]]++; }
  #pragma unroll
  for (int e = 0; e < NE_; e++) hist[tid][e] = loc[e];
  __syncthreads();
  for (int off = 1; off < 256; off <<= 1) {
    int v[NE_];
    #pragma unroll
    for (int e = 0; e < NE_; e++) v[e] = (tid >= off) ? hist[tid - off][e] : 0;
    __syncthreads();
    #pragma unroll
    for (int e = 0; e < NE_; e++) hist[tid][e] += v[e];
    __syncthreads();
  }
  if (tid == 0) {
    int acc = 0;
    for (int e = 0; e < NE_; e++) {
      int c = hist[255][e];
      eoff[e] = acc; counts[e] = c; offs[e] = acc; acc += c;
    }
  }
  __syncthreads();
  int run[NE_];
  #pragma unroll
  for (int e = 0; e < NE_; e++) run[e] = eoff[e] + hist[tid][e] - loc[e];
  #pragma unroll
  for (int i = 0; i < 8; i++) {
    int e = te[i];
    tlist[run[e]++] = tid * 8 + i;
  }
}

// ---------------------------------------------------------------- final mean + head (fp32)
__global__ __launch_bounds__(256) void mean_part_kernel(const float* __restrict__ X,
                                                        float* __restrict__ part) {
  int bd = blockIdx.x * 256 + threadIdx.x;
  int chunk = blockIdx.y;
  int b = bd >> 10, d = bd & 1023;
  float s = 0.f;
  #pragma unroll 4
  for (int i = 0; i < 64; i++) {
    int sidx = chunk * 64 + i;
    s += X[((size_t)b * S_ + sidx) * D_ + d];
  }
  part[chunk * T_ + bd] = s;
}

__global__ __launch_bounds__(256) void mean_final_kernel(const float* __restrict__ part,
                                                         float* __restrict__ hm) {
  int bd = blockIdx.x * 256 + threadIdx.x;
  float s = 0.f;
  #pragma unroll
  for (int c = 0; c < 16; c++) s += part[c * T_ + bd];
  hm[bd] = s * (1.0f / S_);
}

__global__ __launch_bounds__(256) void head_kernel(const float* __restrict__ hm,
    const float* __restrict__ hw, const float* __restrict__ hb,
    float* __restrict__ out) {
  int w = threadIdx.x >> 6;
  int lane = threadIdx.x & 63;
  int c = blockIdx.x * 4 + w;
  const float* row = hw + (size_t)c * D_;
  float acc0 = 0.f, acc1 = 0.f;
  #pragma unroll
  for (int k = 0; k < 4; k++) {
    int d = lane * 4 + k * 256;
    float4 wv = *(const float4*)(row + d);
    float4 h0 = *(const float4*)(hm + d);
    float4 h1 = *(const float4*)(hm + D_ + d);
    acc0 += wv.x * h0.x + wv.y * h0.y + wv.z * h0.z + wv.w * h0.w;
    acc1 += wv.x * h1.x + wv.y * h1.y + wv.z * h1.z + wv.w * h1.w;
  }
  #pragma unroll
  for (int o = 32; o >= 1; o >>= 1) {
    acc0 += __shfl_xor(acc0, o, 64);
    acc1 += __shfl_xor(acc1, o, 64);
  }
  if (lane == 0) {
    float bias = hb[c];
    out[c] = acc0 + bias;
    out[NC_ + c] = acc1 + bias;
  }
}

// ---------------------------------------------------------------- host launch
extern "C" void kernel_launch(void* const* d_in, const int* in_sizes, int n_in,
                              void* d_out, int out_size, void* d_ws, size_t ws_size,
                              hipStream_t stream) {
  const int*   x        = (const int*)d_in[0];
  const float* tok_emb  = (const float*)d_in[1];
  const float* pos_emb  = (const float*)d_in[2];
  const float* in_proj_w= (const float*)d_in[3];
  const float* in_proj_b= (const float*)d_in[4];
  const float* out_w    = (const float*)d_in[5];
  const float* out_b    = (const float*)d_in[6];
  const float* ln1_w    = (const float*)d_in[7];
  const float* ln1_b    = (const float*)d_in[8];
  const float* ln2_w    = (const float*)d_in[9];
  const float* ln2_b    = (const float*)d_in[10];
  const float* gr_w     = (const float*)d_in[11];
  const float* gr_b     = (const float*)d_in[12];
  const float* er_w     = (const float*)d_in[13];
  const float* er_b     = (const float*)d_in[14];
  const float* w1       = (const float*)d_in[15];
  const float* b1       = (const float*)d_in[16];
  const float* w2       = (const float*)d_in[17];
  const float* b2       = (const float*)d_in[18];
  const float* lnf_w    = (const float*)d_in[19];
  const float* lnf_b    = (const float*)d_in[20];
  const float* head_w   = (const float*)d_in[21];
  const float* head_b   = (const float*)d_in[22];

  char* wp = (char*)d_ws;
  auto carve = [&](size_t bytes) -> char* {
    char* p = wp;
    wp += (bytes + 255) & ~(size_t)255;
    return p;
  };
  float*  h      = (float*)carve((size_t)T_ * D_ * 4);
  float*  x1     = (float*)carve((size_t)T_ * D_ * 4);
  __bf16* x1b    = (__bf16*)carve((size_t)T_ * D_ * 2);
  __bf16* qkvb   = (__bf16*)carve((size_t)T_ * 3 * D_ * 2);
  __bf16* attnb  = (__bf16*)carve((size_t)T_ * D_ * 2);
  __bf16* hmidb  = (__bf16*)carve((size_t)T_ * H_ * 2);
  float*  part   = (float*)carve((size_t)16 * T_ * 4);
  float*  hm     = (float*)carve((size_t)B_ * D_ * 4);
  float*  gate   = (float*)carve((size_t)T_ * 4);
  int*    eidx   = (int*)carve((size_t)T_ * 4);
  int*    tlist  = (int*)carve((size_t)T_ * 4);
  int*    counts = (int*)carve(64);
  int*    offs   = (int*)carve(64);

  embed_kernel<<<T_, 256, 0, stream>>>(x, tok_emb, pos_emb, h);

  for (int l = 0; l < L_; l++) {
    // ---- attention half
    ln_kernel<false, true><<<T_, 256, 0, stream>>>(h, ln1_w + l * D_, ln1_b + l * D_,
                                                   nullptr, x1b);
    gemm_mfma<0, 4, false><<<dim3(24, 16, 1), 256, 0, stream>>>(
        x1b, in_proj_w + (size_t)l * 3 * D_ * D_, in_proj_b + (size_t)l * 3 * D_,
        nullptr, qkvb, nullptr, nullptr, nullptr, nullptr, 3 * D_, D_);
    attn_mfma_kernel<<<dim3(S_ / 64, B_ * NH_), 256, 0, stream>>>(qkvb, attnb);
    gemm_mfma<1, 2, false><<<dim3(16, 16, 1), 256, 0, stream>>>(
        attnb, out_w + (size_t)l * D_ * D_, out_b + (size_t)l * D_, h, nullptr,
        nullptr, nullptr, nullptr, nullptr, D_, D_);

    // ---- MoE half
    ln_kernel<true, true><<<T_, 256, 0, stream>>>(h, ln2_w + l * D_, ln2_b + l * D_,
                                                  x1, x1b);
    route_kernel<<<T_, 64, 0, stream>>>(x1,
        gr_w + (size_t)l * D_ * G_, gr_b + (size_t)l * G_,
        er_w + (size_t)l * G_ * D_ * EPG_, er_b + (size_t)l * G_ * EPG_,
        eidx, gate);
    finalize_kernel<<<1, 256, 0, stream>>>(eidx, counts, offs, tlist);

    // w1: [e][D,H] f32, KN layout. N=H, K=D.
    gemm_mfma<2, 4, true><<<dim3(H_ / 128, T_ / 128, NE_), 256, 0, stream>>>(
        x1b, w1 + (size_t)l * NE_ * D_ * H_, b1 + (size_t)l * NE_ * H_, nullptr, hmidb,
        tlist, offs, counts, nullptr, H_, D_);
    // w2: [e][H,D] f32, KN layout. N=D, K=H.
    gemm_mfma<3, 2, true><<<dim3(D_ / 64, T_ / 128, NE_), 256, 0, stream>>>(
        hmidb, w2 + (size_t)l * NE_ * H_ * D_, b2 + (size_t)l * NE_ * D_, h, nullptr,
        tlist, offs, counts, gate, D_, H_);
  }

  ln_kernel<true, false><<<T_, 256, 0, stream>>>(h, lnf_w, lnf_b, x1, nullptr);
  mean_part_kernel<<<dim3(B_ * D_ / 256, 16), 256, 0, stream>>>(x1, part);
  mean_final_kernel<<<B_ * D_ / 256, 256, 0, stream>>>(part, hm);
  head_kernel<<<NC_ / 4, 256, 0, stream>>>(hm, head_w, head_b, (float*)d_out);
}

// Round 5
// 906.035 us; speedup vs baseline: 5.4648x; 1.1443x over previous
//
#include <hip/hip_runtime.h>
#include <hip/hip_bf16.h>
#include <cstdint>
#include <cstddef>

#define D_   1024
#define H_   2048
#define G_   4
#define EPG_ 2
#define NE_  8      // G*EPG
#define NH_  16
#define HD_  64
#define L_   4
#define V_   32000
#define NC_  32000
#define B_   2
#define S_   1024
#define T_   2048   // B*S
#define MAXBLK_ 24  // >= sum_e ceil(cnt_e/128) <= 16+7

typedef __attribute__((__ext_vector_type__(8))) __bf16 bf16x8;
typedef __attribute__((__ext_vector_type__(4))) __bf16 bf16x4;
typedef __attribute__((__ext_vector_type__(4))) float  f32x4;

// async global->LDS, 16B per lane. Dest must be linear (wave base + lane*16).
__device__ __forceinline__ void gl_lds16(const void* g, void* l) {
  __builtin_amdgcn_global_load_lds(
      (const __attribute__((address_space(1))) void*)g,
      (__attribute__((address_space(3))) void*)l, 16, 0, 0);
}

__device__ __forceinline__ float wave_sum(float v) {
  #pragma unroll
  for (int o = 32; o >= 1; o >>= 1) v += __shfl_xor(v, o, 64);
  return v;
}

// ---------------------------------------------------------------- embed
__global__ __launch_bounds__(256) void embed_kernel(const int* __restrict__ x,
    const float* __restrict__ tok, const float* __restrict__ pos,
    float* __restrict__ h) {
  int t = blockIdx.x;
  int tid = threadIdx.x;
  int token = x[t];
  int s = t & (S_ - 1);
  float4 tv = *(const float4*)(tok + (size_t)token * D_ + tid * 4);
  float4 pv = *(const float4*)(pos + (size_t)s * D_ + tid * 4);
  float4 r;
  r.x = tv.x + pv.x; r.y = tv.y + pv.y; r.z = tv.z + pv.z; r.w = tv.w + pv.w;
  *(float4*)(h + (size_t)t * D_ + tid * 4) = r;
}

// ---------------------------------------------------------------- layernorm (block per token)
__device__ __forceinline__ float block_sum256(float v, float* sbuf) {
  v = wave_sum(v);
  int tid = threadIdx.x;
  if ((tid & 63) == 0) sbuf[tid >> 6] = v;
  __syncthreads();
  float r = sbuf[0] + sbuf[1] + sbuf[2] + sbuf[3];
  __syncthreads();
  return r;
}

template<bool F32OUT, bool BFOUT>
__global__ __launch_bounds__(256) void ln_kernel(const float* __restrict__ X,
    const float* __restrict__ w, const float* __restrict__ b,
    float* __restrict__ Yf, __bf16* __restrict__ Yb) {
  __shared__ float sbuf[4];
  int t = blockIdx.x, tid = threadIdx.x;
  const float* xr = X + (size_t)t * D_;
  float4 v = *(const float4*)(xr + tid * 4);
  float sum = v.x + v.y + v.z + v.w;
  float m = block_sum256(sum, sbuf) * (1.0f / D_);
  float dx = v.x - m, dy = v.y - m, dz = v.z - m, dw = v.w - m;
  float vs = dx * dx + dy * dy + dz * dz + dw * dw;
  float var = block_sum256(vs, sbuf) * (1.0f / D_);
  float rs = rsqrtf(var + 1e-5f);
  float4 wv = *(const float4*)(w + tid * 4);
  float4 bv = *(const float4*)(b + tid * 4);
  float4 o;
  o.x = dx * rs * wv.x + bv.x;
  o.y = dy * rs * wv.y + bv.y;
  o.z = dz * rs * wv.z + bv.z;
  o.w = dw * rs * wv.w + bv.w;
  if (F32OUT) *(float4*)(Yf + (size_t)t * D_ + tid * 4) = o;
  if (BFOUT) {
    bf16x4 ob = {(__bf16)o.x, (__bf16)o.y, (__bf16)o.z, (__bf16)o.w};
    *(bf16x4*)(Yb + (size_t)t * D_ + tid * 4) = ob;
  }
}

// ---------------------------------------------------------------- fused ln2 + routing
// 4 tokens/block, 1 wave each. LN in registers -> x1b bf16; router dots on
// normalized values; top-1 group then top-1 expert; writes eidx/gate.
__global__ __launch_bounds__(256) void ln_route_kernel(const float* __restrict__ X,
    const float* __restrict__ lw, const float* __restrict__ lb,
    const float* __restrict__ gw, const float* __restrict__ gb,
    const float* __restrict__ ew, const float* __restrict__ eb,
    __bf16* __restrict__ Yb, int* __restrict__ eidx, float* __restrict__ gate) {
  int wv = threadIdx.x >> 6, lane = threadIdx.x & 63;
  int t = blockIdx.x * 4 + wv;
  const float* xr = X + (size_t)t * D_;
  float4 xv[4];
  #pragma unroll
  for (int k = 0; k < 4; k++) xv[k] = *(const float4*)(xr + lane * 4 + k * 256);
  float s = 0.f;
  #pragma unroll
  for (int k = 0; k < 4; k++) s += xv[k].x + xv[k].y + xv[k].z + xv[k].w;
  float m = wave_sum(s) * (1.0f / D_);
  float vs = 0.f;
  #pragma unroll
  for (int k = 0; k < 4; k++) {
    float a = xv[k].x - m, b2 = xv[k].y - m, c = xv[k].z - m, d = xv[k].w - m;
    vs += a * a + b2 * b2 + c * c + d * d;
  }
  float rs = rsqrtf(wave_sum(vs) * (1.0f / D_) + 1e-5f);
  float y[4][4];
  #pragma unroll
  for (int k = 0; k < 4; k++) {
    int d0 = lane * 4 + k * 256;
    float4 wv4 = *(const float4*)(lw + d0);
    float4 bv4 = *(const float4*)(lb + d0);
    y[k][0] = (xv[k].x - m) * rs * wv4.x + bv4.x;
    y[k][1] = (xv[k].y - m) * rs * wv4.y + bv4.y;
    y[k][2] = (xv[k].z - m) * rs * wv4.z + bv4.z;
    y[k][3] = (xv[k].w - m) * rs * wv4.w + bv4.w;
    bf16x4 ob = {(__bf16)y[k][0], (__bf16)y[k][1], (__bf16)y[k][2], (__bf16)y[k][3]};
    *(bf16x4*)(Yb + (size_t)t * D_ + d0) = ob;
  }
  // group logits
  float g0 = 0, g1 = 0, g2 = 0, g3 = 0;
  #pragma unroll
  for (int k = 0; k < 4; k++)
    #pragma unroll
    for (int j = 0; j < 4; j++) {
      int d = lane * 4 + k * 256 + j;
      float4 gv = *(const float4*)(gw + (size_t)d * G_);
      float yv = y[k][j];
      g0 += yv * gv.x; g1 += yv * gv.y; g2 += yv * gv.z; g3 += yv * gv.w;
    }
  g0 = wave_sum(g0) + gb[0];
  g1 = wave_sum(g1) + gb[1];
  g2 = wave_sum(g2) + gb[2];
  g3 = wave_sum(g3) + gb[3];
  float mx = fmaxf(fmaxf(g0, g1), fmaxf(g2, g3));
  float p0 = __expf(g0 - mx), p1 = __expf(g1 - mx), p2 = __expf(g2 - mx), p3 = __expf(g3 - mx);
  float psum = p0 + p1 + p2 + p3;
  int gidx = 0; float best = g0;
  if (g1 > best) { best = g1; gidx = 1; }
  if (g2 > best) { best = g2; gidx = 2; }
  if (g3 > best) { best = g3; gidx = 3; }
  float gpsel = ((gidx == 0) ? p0 : (gidx == 1) ? p1 : (gidx == 2) ? p2 : p3) / psum;
  // expert logits for selected group
  const float* ewg = ew + (size_t)gidx * D_ * EPG_;
  float e0 = 0, e1 = 0;
  #pragma unroll
  for (int k = 0; k < 4; k++)
    #pragma unroll
    for (int j = 0; j < 4; j++) {
      int d = lane * 4 + k * 256 + j;
      float2 ev = *(const float2*)(ewg + (size_t)d * EPG_);
      e0 += y[k][j] * ev.x; e1 += y[k][j] * ev.y;
    }
  e0 = wave_sum(e0) + eb[gidx * EPG_ + 0];
  e1 = wave_sum(e1) + eb[gidx * EPG_ + 1];
  float em = fmaxf(e0, e1);
  float q0 = __expf(e0 - em), q1 = __expf(e1 - em);
  int ei = (e1 > e0) ? 1 : 0;
  float epsel = ((ei == 0) ? q0 : q1) / (q0 + q1);
  if (lane == 0) {
    eidx[t] = gidx * EPG_ + ei;
    gate[t] = gpsel * epsel;
  }
}

// ---------------------------------------------------------------- finalize: histogram + scan + stable scatter + block list
__global__ __launch_bounds__(256) void finalize_kernel(const int* __restrict__ eidx,
    int* __restrict__ counts, int* __restrict__ offs, int* __restrict__ tlist,
    int* __restrict__ blk) {
  __shared__ int hist[256][NE_];
  __shared__ int eoff[NE_];
  int tid = threadIdx.x;
  int loc[NE_];
  #pragma unroll
  for (int e = 0; e < NE_; e++) loc[e] = 0;
  int te[8];
  #pragma unroll
  for (int i = 0; i < 8; i++) { te[i] = eidx[tid * 8 + i]; loc[te[i]]++; }
  #pragma unroll
  for (int e = 0; e < NE_; e++) hist[tid][e] = loc[e];
  __syncthreads();
  for (int off = 1; off < 256; off <<= 1) {
    int v[NE_];
    #pragma unroll
    for (int e = 0; e < NE_; e++) v[e] = (tid >= off) ? hist[tid - off][e] : 0;
    __syncthreads();
    #pragma unroll
    for (int e = 0; e < NE_; e++) hist[tid][e] += v[e];
    __syncthreads();
  }
  if (tid == 0) {
    int acc = 0, nb = 0;
    for (int e = 0; e < NE_; e++) {
      int c = hist[255][e];
      eoff[e] = acc; counts[e] = c; offs[e] = acc; acc += c;
      for (int mt = 0; mt * 128 < c; mt++) blk[nb++] = e | (mt << 8);
    }
    for (; nb < MAXBLK_; nb++) blk[nb] = -1;
  }
  __syncthreads();
  int run[NE_];
  #pragma unroll
  for (int e = 0; e < NE_; e++) run[e] = eoff[e] + hist[tid][e] - loc[e];
  #pragma unroll
  for (int i = 0; i < 8; i++) {
    int e = te[i];
    tlist[run[e]++] = tid * 8 + i;
  }
}

// ---------------------------------------------------------------- bf16 MFMA GEMM
// C[M,N] = A[M,K] @ Wmat + bias, A bf16, W f32 (converted at stage time).
// KN=false: W stored [N,K]; KN=true: W stored [K,N]. Tile 128 x (NF*32).
// 4 waves 2x2. A via global_load_lds (pre-swizzled src); B reg-staged with
// one-step register prefetch (issue-early / write-late).
// MODE 0: Cb = acc+bias (bf16)                [qkv]
// MODE 1: Cf += acc+bias (f32 residual)       [out-proj]
// MODE 2: gather rows; Cb = relu(acc+bias)    [moe w1]
// MODE 3: gather rows; Cf += gate*(acc+bias)  [moe w2]
template<int MODE, int NF, bool KN>
__global__ __launch_bounds__(256, 2) void gemm_mfma(
    const __bf16* __restrict__ A, const float* __restrict__ W,
    const float* __restrict__ bias, float* __restrict__ Cf,
    __bf16* __restrict__ Cb, const int* __restrict__ tlist,
    const int* __restrict__ offs, const int* __restrict__ counts,
    const float* __restrict__ gate, const int* __restrict__ blk,
    int N, int K) {
  __shared__ __bf16 As[128 * 64];        // [row][8 units of 8 bf16], units swizzled
  __shared__ __bf16 Bs[NF * 32 * 64];
  int e = 0, mt = blockIdx.y, cnt = T_;
  if (MODE >= 2) {
    int bv = blk[blockIdx.y];
    if (bv < 0) return;
    e = bv & 255; mt = bv >> 8;
    cnt = counts[e];
  }
  int row0 = mt * 128;
  int lbase = (MODE >= 2) ? offs[e] : 0;
  int col0 = blockIdx.x * (NF * 32);
  const float* Wp = W + (size_t)e * N * K;
  const float* bp = bias + (size_t)e * N;
  int tid = threadIdx.x;
  int w = tid >> 6, lane = tid & 63, lq = lane & 15, lg = lane >> 4;
  int wr = w >> 1, wc = w & 1;

  // A staging source pointers (inverse-swizzled 16B units)
  const __bf16* asrc[4];
  #pragma unroll
  for (int it = 0; it < 4; it++) {
    int v = it * 256 + tid;
    int r = v >> 3, u = v & 7;
    int gr = row0 + r;
    long rowidx;
    if (MODE >= 2) rowidx = tlist[lbase + ((gr < cnt) ? gr : cnt - 1)];
    else rowidx = gr;
    asrc[it] = A + (size_t)rowidx * K + (u ^ (r & 7)) * 8;
  }
  // B staging descriptors
  const float* bsrc[NF];
  int bdst[NF];
  #pragma unroll
  for (int it = 0; it < NF; it++) {
    if (!KN) {
      int v = it * 256 + tid;
      int n = v >> 3, u = v & 7;
      bsrc[it] = Wp + (size_t)(col0 + n) * K + u * 8;
      bdst[it] = n * 64 + (u ^ (n & 7)) * 8;
    } else {
      int v = it * 256 + tid;
      int n = v & (NF * 32 - 1), u = v / (NF * 32);
      bsrc[it] = Wp + (size_t)(u * 8) * N + col0 + n;
      bdst[it] = n * 64 + (u ^ (n & 7)) * 8;
    }
  }

  float br0[NF * 8], br1[NF * 8];
  f32x4 acc[4][NF] = {};

  auto loadB = [&](float* br, int k0) {
    #pragma unroll
    for (int it = 0; it < NF; it++) {
      if (!KN) {
        float4 f0 = *(const float4*)(bsrc[it] + k0);
        float4 f1 = *(const float4*)(bsrc[it] + k0 + 4);
        br[it * 8 + 0] = f0.x; br[it * 8 + 1] = f0.y;
        br[it * 8 + 2] = f0.z; br[it * 8 + 3] = f0.w;
        br[it * 8 + 4] = f1.x; br[it * 8 + 5] = f1.y;
        br[it * 8 + 6] = f1.z; br[it * 8 + 7] = f1.w;
      } else {
        #pragma unroll
        for (int j = 0; j < 8; j++)
          br[it * 8 + j] = bsrc[it][(size_t)(k0 + j) * N];
      }
    }
  };
  auto writeB = [&](const float* br) {
    #pragma unroll
    for (int it = 0; it < NF; it++) {
      bf16x8 bb = {(__bf16)br[it * 8 + 0], (__bf16)br[it * 8 + 1],
                   (__bf16)br[it * 8 + 2], (__bf16)br[it * 8 + 3],
                   (__bf16)br[it * 8 + 4], (__bf16)br[it * 8 + 5],
                   (__bf16)br[it * 8 + 6], (__bf16)br[it * 8 + 7]};
      *(bf16x8*)&Bs[bdst[it]] = bb;
    }
  };
  auto stageA = [&](int k0) {
    #pragma unroll
    for (int it = 0; it < 4; it++)
      gl_lds16(asrc[it] + k0, &As[(it * 256 + tid) * 8]);
  };
  auto mfmaPhase = [&]() {
    #pragma unroll
    for (int kk = 0; kk < 2; kk++) {
      bf16x8 a[4], b[NF];
      int us = ((lg + kk * 4) ^ (lq & 7)) * 8;
      #pragma unroll
      for (int fi = 0; fi < 4; fi++)
        a[fi] = *(const bf16x8*)&As[(wr * 64 + fi * 16 + lq) * 64 + us];
      #pragma unroll
      for (int fj = 0; fj < NF; fj++)
        b[fj] = *(const bf16x8*)&Bs[(wc * (NF * 16) + fj * 16 + lq) * 64 + us];
      #pragma unroll
      for (int fi = 0; fi < 4; fi++)
        #pragma unroll
        for (int fj = 0; fj < NF; fj++)
          acc[fi][fj] = __builtin_amdgcn_mfma_f32_16x16x32_bf16(a[fi], b[fj], acc[fi][fj], 0, 0, 0);
    }
  };

  loadB(br0, 0);
  for (int k0 = 0; k0 < K; k0 += 128) {
    stageA(k0);
    writeB(br0);
    loadB(br1, k0 + 64);           // prefetch: overlaps barrier drain + MFMA
    __syncthreads();
    mfmaPhase();
    __syncthreads();
    stageA(k0 + 64);
    writeB(br1);
    if (k0 + 128 < K) loadB(br0, k0 + 128);
    __syncthreads();
    mfmaPhase();
    __syncthreads();
  }

  #pragma unroll
  for (int fi = 0; fi < 4; fi++) {
    #pragma unroll
    for (int v = 0; v < 4; v++) {
      int r = row0 + wr * 64 + fi * 16 + lg * 4 + v;
      long orow;
      float gv = 1.f;
      if (MODE >= 2) {
        if (r >= cnt) continue;
        orow = tlist[lbase + r];
        if (MODE == 3) gv = gate[orow];
      } else {
        orow = r;
      }
      #pragma unroll
      for (int fj = 0; fj < NF; fj++) {
        int c = col0 + wc * (NF * 16) + fj * 16 + lq;
        float val = acc[fi][fj][v] + bp[c];
        if (MODE == 0)      Cb[orow * N + c] = (__bf16)val;
        else if (MODE == 1) Cf[orow * N + c] += val;
        else if (MODE == 2) Cb[orow * N + c] = (__bf16)fmaxf(val, 0.f);
        else                Cf[orow * N + c] += gv * val;
      }
    }
  }
}

// ---------------------------------------------------------------- flash attention, bf16 MFMA
#define SC_LOG2 0.18033688011112042f   // (1/sqrt(64)) * log2(e)
__global__ __launch_bounds__(256) void attn_mfma_kernel(const __bf16* __restrict__ qkv,
                                                        __bf16* __restrict__ out) {
  __shared__ __bf16 Ks[64][72];
  __shared__ __bf16 Vt[64][72];   // transposed: [d][kv]
  __shared__ __bf16 Ps[64][72];
  int tid = threadIdx.x;
  int w = tid >> 6, lane = tid & 63, lq = lane & 15, lg = lane >> 4;
  int qt = (S_ / 64 - 1) - blockIdx.x;   // heaviest blocks dispatch first
  int b = blockIdx.y >> 4, hh = blockIdx.y & 15;
  const __bf16* qbase = qkv + (size_t)b * S_ * 3 * D_ + hh * HD_;

  bf16x8 qa[2];
  {
    const __bf16* qp = qbase + (size_t)(qt * 64 + w * 16 + lq) * 3 * D_ + lg * 8;
    qa[0] = *(const bf16x8*)qp;
    qa[1] = *(const bf16x8*)(qp + 32);
  }

  f32x4 o[4] = {};
  float m_[4] = {-1e30f, -1e30f, -1e30f, -1e30f};
  float l_[4] = {0.f, 0.f, 0.f, 0.f};

  for (int kt = 0; kt <= qt; kt++) {
    #pragma unroll
    for (int it = 0; it < 2; it++) {
      int idx = tid + it * 256;
      int row = idx >> 3, c8 = idx & 7;
      const __bf16* kp = qbase + (size_t)(kt * 64 + row) * 3 * D_ + D_ + c8 * 8;
      *(bf16x8*)&Ks[row][c8 * 8] = *(const bf16x8*)kp;
      bf16x8 vv = *(const bf16x8*)(kp + D_);
      #pragma unroll
      for (int j = 0; j < 8; j++) Vt[c8 * 8 + j][row] = vv[j];
    }
    __syncthreads();

    f32x4 s[4] = {};
    #pragma unroll
    for (int kk = 0; kk < 2; kk++)
      #pragma unroll
      for (int fc = 0; fc < 4; fc++) {
        bf16x8 kf = *(const bf16x8*)&Ks[fc * 16 + lq][lg * 8 + kk * 32];
        s[fc] = __builtin_amdgcn_mfma_f32_16x16x32_bf16(qa[kk], kf, s[fc], 0, 0, 0);
      }

    #pragma unroll
    for (int fc = 0; fc < 4; fc++)
      #pragma unroll
      for (int v = 0; v < 4; v++) {
        float sv = s[fc][v] * SC_LOG2;
        if (kt == qt && (fc * 16 + lq) > (w * 16 + lg * 4 + v)) sv = -1e30f;
        s[fc][v] = sv;
      }

    float corr[4];
    #pragma unroll
    for (int v = 0; v < 4; v++) {
      float rm = fmaxf(fmaxf(s[0][v], s[1][v]), fmaxf(s[2][v], s[3][v]));
      #pragma unroll
      for (int o2 = 8; o2 >= 1; o2 >>= 1) rm = fmaxf(rm, __shfl_xor(rm, o2, 64));
      float mnew = fmaxf(m_[v], rm);
      float cc = exp2f(m_[v] - mnew);
      float rs = 0.f;
      #pragma unroll
      for (int fc = 0; fc < 4; fc++) {
        float p = exp2f(s[fc][v] - mnew);
        s[fc][v] = p; rs += p;
      }
      l_[v] = l_[v] * cc + rs;
      m_[v] = mnew;
      corr[v] = cc;
    }
    #pragma unroll
    for (int dc = 0; dc < 4; dc++)
      #pragma unroll
      for (int v = 0; v < 4; v++) o[dc][v] *= corr[v];

    #pragma unroll
    for (int fc = 0; fc < 4; fc++)
      #pragma unroll
      for (int v = 0; v < 4; v++)
        Ps[w * 16 + lg * 4 + v][fc * 16 + lq] = (__bf16)s[fc][v];
    __syncthreads();

    #pragma unroll
    for (int kk = 0; kk < 2; kk++) {
      bf16x8 pa = *(const bf16x8*)&Ps[w * 16 + lq][lg * 8 + kk * 32];
      #pragma unroll
      for (int dc = 0; dc < 4; dc++) {
        bf16x8 vb = *(const bf16x8*)&Vt[dc * 16 + lq][lg * 8 + kk * 32];
        o[dc] = __builtin_amdgcn_mfma_f32_16x16x32_bf16(pa, vb, o[dc], 0, 0, 0);
      }
    }
    __syncthreads();
  }

  #pragma unroll
  for (int v = 0; v < 4; v++) {
    float ls = l_[v];
    #pragma unroll
    for (int o2 = 8; o2 >= 1; o2 >>= 1) ls += __shfl_xor(ls, o2, 64);
    float inv = 1.0f / ls;
    int row = qt * 64 + w * 16 + lg * 4 + v;
    __bf16* op = out + ((size_t)b * S_ + row) * D_ + hh * HD_;
    #pragma unroll
    for (int dc = 0; dc < 4; dc++)
      op[dc * 16 + lq] = (__bf16)(o[dc][v] * inv);
  }
}

// ---------------------------------------------------------------- final mean + head (fp32)
__global__ __launch_bounds__(256) void mean_part_kernel(const float* __restrict__ X,
                                                        float* __restrict__ part) {
  int bd = blockIdx.x * 256 + threadIdx.x;
  int chunk = blockIdx.y;
  int b = bd >> 10, d = bd & 1023;
  float s = 0.f;
  #pragma unroll 4
  for (int i = 0; i < 64; i++) {
    int sidx = chunk * 64 + i;
    s += X[((size_t)b * S_ + sidx) * D_ + d];
  }
  part[chunk * T_ + bd] = s;
}

__global__ __launch_bounds__(256) void mean_final_kernel(const float* __restrict__ part,
                                                         float* __restrict__ hm) {
  int bd = blockIdx.x * 256 + threadIdx.x;
  float s = 0.f;
  #pragma unroll
  for (int c = 0; c < 16; c++) s += part[c * T_ + bd];
  hm[bd] = s * (1.0f / S_);
}

__global__ __launch_bounds__(256) void head_kernel(const float* __restrict__ hm,
    const float* __restrict__ hw, const float* __restrict__ hb,
    float* __restrict__ out) {
  int w = threadIdx.x >> 6;
  int lane = threadIdx.x & 63;
  int c = blockIdx.x * 4 + w;
  const float* row = hw + (size_t)c * D_;
  float acc0 = 0.f, acc1 = 0.f;
  #pragma unroll
  for (int k = 0; k < 4; k++) {
    int d = lane * 4 + k * 256;
    float4 wv = *(const float4*)(row + d);
    float4 h0 = *(const float4*)(hm + d);
    float4 h1 = *(const float4*)(hm + D_ + d);
    acc0 += wv.x * h0.x + wv.y * h0.y + wv.z * h0.z + wv.w * h0.w;
    acc1 += wv.x * h1.x + wv.y * h1.y + wv.z * h1.z + wv.w * h1.w;
  }
  #pragma unroll
  for (int o = 32; o >= 1; o >>= 1) {
    acc0 += __shfl_xor(acc0, o, 64);
    acc1 += __shfl_xor(acc1, o, 64);
  }
  if (lane == 0) {
    float bias = hb[c];
    out[c] = acc0 + bias;
    out[NC_ + c] = acc1 + bias;
  }
}

// ---------------------------------------------------------------- host launch
extern "C" void kernel_launch(void* const* d_in, const int* in_sizes, int n_in,
                              void* d_out, int out_size, void* d_ws, size_t ws_size,
                              hipStream_t stream) {
  const int*   x        = (const int*)d_in[0];
  const float* tok_emb  = (const float*)d_in[1];
  const float* pos_emb  = (const float*)d_in[2];
  const float* in_proj_w= (const float*)d_in[3];
  const float* in_proj_b= (const float*)d_in[4];
  const float* out_w    = (const float*)d_in[5];
  const float* out_b    = (const float*)d_in[6];
  const float* ln1_w    = (const float*)d_in[7];
  const float* ln1_b    = (const float*)d_in[8];
  const float* ln2_w    = (const float*)d_in[9];
  const float* ln2_b    = (const float*)d_in[10];
  const float* gr_w     = (const float*)d_in[11];
  const float* gr_b     = (const float*)d_in[12];
  const float* er_w     = (const float*)d_in[13];
  const float* er_b     = (const float*)d_in[14];
  const float* w1       = (const float*)d_in[15];
  const float* b1       = (const float*)d_in[16];
  const float* w2       = (const float*)d_in[17];
  const float* b2       = (const float*)d_in[18];
  const float* lnf_w    = (const float*)d_in[19];
  const float* lnf_b    = (const float*)d_in[20];
  const float* head_w   = (const float*)d_in[21];
  const float* head_b   = (const float*)d_in[22];

  char* wp = (char*)d_ws;
  auto carve = [&](size_t bytes) -> char* {
    char* p = wp;
    wp += (bytes + 255) & ~(size_t)255;
    return p;
  };
  float*  h      = (float*)carve((size_t)T_ * D_ * 4);
  float*  x1     = (float*)carve((size_t)T_ * D_ * 4);
  __bf16* x1b    = (__bf16*)carve((size_t)T_ * D_ * 2);
  __bf16* qkvb   = (__bf16*)carve((size_t)T_ * 3 * D_ * 2);
  __bf16* attnb  = (__bf16*)carve((size_t)T_ * D_ * 2);
  __bf16* hmidb  = (__bf16*)carve((size_t)T_ * H_ * 2);
  float*  part   = (float*)carve((size_t)16 * T_ * 4);
  float*  hm     = (float*)carve((size_t)B_ * D_ * 4);
  float*  gate   = (float*)carve((size_t)T_ * 4);
  int*    eidx   = (int*)carve((size_t)T_ * 4);
  int*    tlist  = (int*)carve((size_t)T_ * 4);
  int*    counts = (int*)carve(64);
  int*    offs   = (int*)carve(64);
  int*    blk    = (int*)carve(MAXBLK_ * 4);

  embed_kernel<<<T_, 256, 0, stream>>>(x, tok_emb, pos_emb, h);

  for (int l = 0; l < L_; l++) {
    // ---- attention half
    ln_kernel<false, true><<<T_, 256, 0, stream>>>(h, ln1_w + l * D_, ln1_b + l * D_,
                                                   nullptr, x1b);
    gemm_mfma<0, 4, false><<<dim3(24, 16, 1), 256, 0, stream>>>(
        x1b, in_proj_w + (size_t)l * 3 * D_ * D_, in_proj_b + (size_t)l * 3 * D_,
        nullptr, qkvb, nullptr, nullptr, nullptr, nullptr, nullptr, 3 * D_, D_);
    attn_mfma_kernel<<<dim3(S_ / 64, B_ * NH_), 256, 0, stream>>>(qkvb, attnb);
    gemm_mfma<1, 2, false><<<dim3(16, 16, 1), 256, 0, stream>>>(
        attnb, out_w + (size_t)l * D_ * D_, out_b + (size_t)l * D_, h, nullptr,
        nullptr, nullptr, nullptr, nullptr, nullptr, D_, D_);

    // ---- MoE half (fused ln2 + route)
    ln_route_kernel<<<T_ / 4, 256, 0, stream>>>(h,
        ln2_w + l * D_, ln2_b + l * D_,
        gr_w + (size_t)l * D_ * G_, gr_b + (size_t)l * G_,
        er_w + (size_t)l * G_ * D_ * EPG_, er_b + (size_t)l * G_ * EPG_,
        x1b, eidx, gate);
    finalize_kernel<<<1, 256, 0, stream>>>(eidx, counts, offs, tlist, blk);

    // w1: [e][D,H] f32, KN layout. N=H, K=D.
    gemm_mfma<2, 4, true><<<dim3(H_ / 128, MAXBLK_, 1), 256, 0, stream>>>(
        x1b, w1 + (size_t)l * NE_ * D_ * H_, b1 + (size_t)l * NE_ * H_, nullptr, hmidb,
        tlist, offs, counts, nullptr, blk, H_, D_);
    // w2: [e][H,D] f32, KN layout. N=D, K=H.
    gemm_mfma<3, 2, true><<<dim3(D_ / 64, MAXBLK_, 1), 256, 0, stream>>>(
        hmidb, w2 + (size_t)l * NE_ * H_ * D_, b2 + (size_t)l * NE_ * D_, h, nullptr,
        tlist, offs, counts, gate, blk, D_, H_);
  }

  ln_kernel<true, false><<<T_, 256, 0, stream>>>(h, lnf_w, lnf_b, x1, nullptr);
  mean_part_kernel<<<dim3(B_ * D_ / 256, 16), 256, 0, stream>>>(x1, part);
  mean_final_kernel<<<B_ * D_ / 256, 256, 0, stream>>>(part, hm);
  head_kernel<<<NC_ / 4, 256, 0, stream>>>(hm, head_w, head_b, (float*)d_out);
}

// Round 6
// 888.154 us; speedup vs baseline: 5.5748x; 1.0201x over previous
//
#include <hip/hip_runtime.h>
#include <hip/hip_bf16.h>
#include <cstdint>
#include <cstddef>

#define D_   1024
#define H_   2048
#define G_   4
#define EPG_ 2
#define NE_  8      // G*EPG
#define NH_  16
#define HD_  64
#define L_   4
#define V_   32000
#define NC_  32000
#define B_   2
#define S_   1024
#define T_   2048   // B*S
#define MAXBLK_ 24  // >= sum_e ceil(cnt_e/128) <= 16+7
#define QB_  128    // attention q-tile

typedef __attribute__((__ext_vector_type__(8))) __bf16 bf16x8;
typedef __attribute__((__ext_vector_type__(4))) __bf16 bf16x4;
typedef __attribute__((__ext_vector_type__(4))) float  f32x4;

// async global->LDS, 16B per lane. Dest must be linear (wave base + lane*16).
__device__ __forceinline__ void gl_lds16(const void* g, void* l) {
  __builtin_amdgcn_global_load_lds(
      (const __attribute__((address_space(1))) void*)g,
      (__attribute__((address_space(3))) void*)l, 16, 0, 0);
}

__device__ __forceinline__ float wave_sum(float v) {
  #pragma unroll
  for (int o = 32; o >= 1; o >>= 1) v += __shfl_xor(v, o, 64);
  return v;
}

// ---------------------------------------------------------------- embed
__global__ __launch_bounds__(256) void embed_kernel(const int* __restrict__ x,
    const float* __restrict__ tok, const float* __restrict__ pos,
    float* __restrict__ h) {
  int t = blockIdx.x;
  int tid = threadIdx.x;
  int token = x[t];
  int s = t & (S_ - 1);
  float4 tv = *(const float4*)(tok + (size_t)token * D_ + tid * 4);
  float4 pv = *(const float4*)(pos + (size_t)s * D_ + tid * 4);
  float4 r;
  r.x = tv.x + pv.x; r.y = tv.y + pv.y; r.z = tv.z + pv.z; r.w = tv.w + pv.w;
  *(float4*)(h + (size_t)t * D_ + tid * 4) = r;
}

// ---------------------------------------------------------------- layernorm (block per token)
__device__ __forceinline__ float block_sum256(float v, float* sbuf) {
  v = wave_sum(v);
  int tid = threadIdx.x;
  if ((tid & 63) == 0) sbuf[tid >> 6] = v;
  __syncthreads();
  float r = sbuf[0] + sbuf[1] + sbuf[2] + sbuf[3];
  __syncthreads();
  return r;
}

template<bool F32OUT, bool BFOUT>
__global__ __launch_bounds__(256) void ln_kernel(const float* __restrict__ X,
    const float* __restrict__ w, const float* __restrict__ b,
    float* __restrict__ Yf, __bf16* __restrict__ Yb) {
  __shared__ float sbuf[4];
  int t = blockIdx.x, tid = threadIdx.x;
  const float* xr = X + (size_t)t * D_;
  float4 v = *(const float4*)(xr + tid * 4);
  float sum = v.x + v.y + v.z + v.w;
  float m = block_sum256(sum, sbuf) * (1.0f / D_);
  float dx = v.x - m, dy = v.y - m, dz = v.z - m, dw = v.w - m;
  float vs = dx * dx + dy * dy + dz * dz + dw * dw;
  float var = block_sum256(vs, sbuf) * (1.0f / D_);
  float rs = rsqrtf(var + 1e-5f);
  float4 wv = *(const float4*)(w + tid * 4);
  float4 bv = *(const float4*)(b + tid * 4);
  float4 o;
  o.x = dx * rs * wv.x + bv.x;
  o.y = dy * rs * wv.y + bv.y;
  o.z = dz * rs * wv.z + bv.z;
  o.w = dw * rs * wv.w + bv.w;
  if (F32OUT) *(float4*)(Yf + (size_t)t * D_ + tid * 4) = o;
  if (BFOUT) {
    bf16x4 ob = {(__bf16)o.x, (__bf16)o.y, (__bf16)o.z, (__bf16)o.w};
    *(bf16x4*)(Yb + (size_t)t * D_ + tid * 4) = ob;
  }
}

// ---------------------------------------------------------------- fused ln2 + routing
__global__ __launch_bounds__(256) void ln_route_kernel(const float* __restrict__ X,
    const float* __restrict__ lw, const float* __restrict__ lb,
    const float* __restrict__ gw, const float* __restrict__ gb,
    const float* __restrict__ ew, const float* __restrict__ eb,
    __bf16* __restrict__ Yb, int* __restrict__ eidx, float* __restrict__ gate) {
  int wv = threadIdx.x >> 6, lane = threadIdx.x & 63;
  int t = blockIdx.x * 4 + wv;
  const float* xr = X + (size_t)t * D_;
  float4 xv[4];
  #pragma unroll
  for (int k = 0; k < 4; k++) xv[k] = *(const float4*)(xr + lane * 4 + k * 256);
  float s = 0.f;
  #pragma unroll
  for (int k = 0; k < 4; k++) s += xv[k].x + xv[k].y + xv[k].z + xv[k].w;
  float m = wave_sum(s) * (1.0f / D_);
  float vs = 0.f;
  #pragma unroll
  for (int k = 0; k < 4; k++) {
    float a = xv[k].x - m, b2 = xv[k].y - m, c = xv[k].z - m, d = xv[k].w - m;
    vs += a * a + b2 * b2 + c * c + d * d;
  }
  float rs = rsqrtf(wave_sum(vs) * (1.0f / D_) + 1e-5f);
  float y[4][4];
  #pragma unroll
  for (int k = 0; k < 4; k++) {
    int d0 = lane * 4 + k * 256;
    float4 wv4 = *(const float4*)(lw + d0);
    float4 bv4 = *(const float4*)(lb + d0);
    y[k][0] = (xv[k].x - m) * rs * wv4.x + bv4.x;
    y[k][1] = (xv[k].y - m) * rs * wv4.y + bv4.y;
    y[k][2] = (xv[k].z - m) * rs * wv4.z + bv4.z;
    y[k][3] = (xv[k].w - m) * rs * wv4.w + bv4.w;
    bf16x4 ob = {(__bf16)y[k][0], (__bf16)y[k][1], (__bf16)y[k][2], (__bf16)y[k][3]};
    *(bf16x4*)(Yb + (size_t)t * D_ + d0) = ob;
  }
  float g0 = 0, g1 = 0, g2 = 0, g3 = 0;
  #pragma unroll
  for (int k = 0; k < 4; k++)
    #pragma unroll
    for (int j = 0; j < 4; j++) {
      int d = lane * 4 + k * 256 + j;
      float4 gv = *(const float4*)(gw + (size_t)d * G_);
      float yv = y[k][j];
      g0 += yv * gv.x; g1 += yv * gv.y; g2 += yv * gv.z; g3 += yv * gv.w;
    }
  g0 = wave_sum(g0) + gb[0];
  g1 = wave_sum(g1) + gb[1];
  g2 = wave_sum(g2) + gb[2];
  g3 = wave_sum(g3) + gb[3];
  float mx = fmaxf(fmaxf(g0, g1), fmaxf(g2, g3));
  float p0 = __expf(g0 - mx), p1 = __expf(g1 - mx), p2 = __expf(g2 - mx), p3 = __expf(g3 - mx);
  float psum = p0 + p1 + p2 + p3;
  int gidx = 0; float best = g0;
  if (g1 > best) { best = g1; gidx = 1; }
  if (g2 > best) { best = g2; gidx = 2; }
  if (g3 > best) { best = g3; gidx = 3; }
  float gpsel = ((gidx == 0) ? p0 : (gidx == 1) ? p1 : (gidx == 2) ? p2 : p3) / psum;
  const float* ewg = ew + (size_t)gidx * D_ * EPG_;
  float e0 = 0, e1 = 0;
  #pragma unroll
  for (int k = 0; k < 4; k++)
    #pragma unroll
    for (int j = 0; j < 4; j++) {
      int d = lane * 4 + k * 256 + j;
      float2 ev = *(const float2*)(ewg + (size_t)d * EPG_);
      e0 += y[k][j] * ev.x; e1 += y[k][j] * ev.y;
    }
  e0 = wave_sum(e0) + eb[gidx * EPG_ + 0];
  e1 = wave_sum(e1) + eb[gidx * EPG_ + 1];
  float em = fmaxf(e0, e1);
  float q0 = __expf(e0 - em), q1 = __expf(e1 - em);
  int ei = (e1 > e0) ? 1 : 0;
  float epsel = ((ei == 0) ? q0 : q1) / (q0 + q1);
  if (lane == 0) {
    eidx[t] = gidx * EPG_ + ei;
    gate[t] = gpsel * epsel;
  }
}

// ---------------------------------------------------------------- finalize
__global__ __launch_bounds__(256) void finalize_kernel(const int* __restrict__ eidx,
    int* __restrict__ counts, int* __restrict__ offs, int* __restrict__ tlist,
    int* __restrict__ blk) {
  __shared__ int hist[256][NE_];
  __shared__ int eoff[NE_];
  int tid = threadIdx.x;
  int loc[NE_];
  #pragma unroll
  for (int e = 0; e < NE_; e++) loc[e] = 0;
  int te[8];
  #pragma unroll
  for (int i = 0; i < 8; i++) { te[i] = eidx[tid * 8 + i]; loc[te[i]]++; }
  #pragma unroll
  for (int e = 0; e < NE_; e++) hist[tid][e] = loc[e];
  __syncthreads();
  for (int off = 1; off < 256; off <<= 1) {
    int v[NE_];
    #pragma unroll
    for (int e = 0; e < NE_; e++) v[e] = (tid >= off) ? hist[tid - off][e] : 0;
    __syncthreads();
    #pragma unroll
    for (int e = 0; e < NE_; e++) hist[tid][e] += v[e];
    __syncthreads();
  }
  if (tid == 0) {
    int acc = 0, nb = 0;
    for (int e = 0; e < NE_; e++) {
      int c = hist[255][e];
      eoff[e] = acc; counts[e] = c; offs[e] = acc; acc += c;
      for (int mt = 0; mt * 128 < c; mt++) blk[nb++] = e | (mt << 8);
    }
    for (; nb < MAXBLK_; nb++) blk[nb] = -1;
  }
  __syncthreads();
  int run[NE_];
  #pragma unroll
  for (int e = 0; e < NE_; e++) run[e] = eoff[e] + hist[tid][e] - loc[e];
  #pragma unroll
  for (int i = 0; i < 8; i++) {
    int e = te[i];
    tlist[run[e]++] = tid * 8 + i;
  }
}

// ---------------------------------------------------------------- bf16 MFMA GEMM
// MODE 0: Cb = acc+bias (bf16)                       [qkv]
// MODE 1: Cf += acc+bias (f32 residual)              [out-proj]
// MODE 2: gather rows via tlist; Cb[compact] = relu  [moe w1]
// MODE 3: linear rows from compact; scatter to h     [moe w2]
template<int MODE, int NF, bool KN>
__global__ __launch_bounds__(256, 2) void gemm_mfma(
    const __bf16* __restrict__ A, const float* __restrict__ W,
    const float* __restrict__ bias, float* __restrict__ Cf,
    __bf16* __restrict__ Cb, const int* __restrict__ tlist,
    const int* __restrict__ offs, const int* __restrict__ counts,
    const float* __restrict__ gate, const int* __restrict__ blk,
    int N, int K) {
  __shared__ __bf16 As[128 * 64];
  __shared__ __bf16 Bs[NF * 32 * 64];
  int e = 0, mt = blockIdx.y, cnt = T_;
  if (MODE >= 2) {
    int bv = blk[blockIdx.y];
    if (bv < 0) return;
    e = bv & 255; mt = bv >> 8;
    cnt = counts[e];
  }
  int row0 = mt * 128;
  int lbase = (MODE >= 2) ? offs[e] : 0;
  int col0 = blockIdx.x * (NF * 32);
  const float* Wp = W + (size_t)e * N * K;
  const float* bp = bias + (size_t)e * N;
  int tid = threadIdx.x;
  int w = tid >> 6, lane = tid & 63, lq = lane & 15, lg = lane >> 4;
  int wr = w >> 1, wc = w & 1;

  const __bf16* asrc[4];
  #pragma unroll
  for (int it = 0; it < 4; it++) {
    int v = it * 256 + tid;
    int r = v >> 3, u = v & 7;
    int gr = row0 + r;
    long rowidx;
    if (MODE == 2) rowidx = tlist[lbase + ((gr < cnt) ? gr : cnt - 1)];
    else if (MODE == 3) rowidx = lbase + ((gr < cnt) ? gr : cnt - 1);
    else rowidx = gr;
    asrc[it] = A + (size_t)rowidx * K + (u ^ (r & 7)) * 8;
  }
  const float* bsrc[NF];
  int bdst[NF];
  #pragma unroll
  for (int it = 0; it < NF; it++) {
    if (!KN) {
      int v = it * 256 + tid;
      int n = v >> 3, u = v & 7;
      bsrc[it] = Wp + (size_t)(col0 + n) * K + u * 8;
      bdst[it] = n * 64 + (u ^ (n & 7)) * 8;
    } else {
      int v = it * 256 + tid;
      int n = v & (NF * 32 - 1), u = v / (NF * 32);
      bsrc[it] = Wp + (size_t)(u * 8) * N + col0 + n;
      bdst[it] = n * 64 + (u ^ (n & 7)) * 8;
    }
  }

  float br0[NF * 8], br1[NF * 8];
  f32x4 acc[4][NF] = {};

  auto loadB = [&](float* br, int k0) {
    #pragma unroll
    for (int it = 0; it < NF; it++) {
      if (!KN) {
        float4 f0 = *(const float4*)(bsrc[it] + k0);
        float4 f1 = *(const float4*)(bsrc[it] + k0 + 4);
        br[it * 8 + 0] = f0.x; br[it * 8 + 1] = f0.y;
        br[it * 8 + 2] = f0.z; br[it * 8 + 3] = f0.w;
        br[it * 8 + 4] = f1.x; br[it * 8 + 5] = f1.y;
        br[it * 8 + 6] = f1.z; br[it * 8 + 7] = f1.w;
      } else {
        #pragma unroll
        for (int j = 0; j < 8; j++)
          br[it * 8 + j] = bsrc[it][(size_t)(k0 + j) * N];
      }
    }
  };
  auto writeB = [&](const float* br) {
    #pragma unroll
    for (int it = 0; it < NF; it++) {
      bf16x8 bb = {(__bf16)br[it * 8 + 0], (__bf16)br[it * 8 + 1],
                   (__bf16)br[it * 8 + 2], (__bf16)br[it * 8 + 3],
                   (__bf16)br[it * 8 + 4], (__bf16)br[it * 8 + 5],
                   (__bf16)br[it * 8 + 6], (__bf16)br[it * 8 + 7]};
      *(bf16x8*)&Bs[bdst[it]] = bb;
    }
  };
  auto stageA = [&](int k0) {
    #pragma unroll
    for (int it = 0; it < 4; it++)
      gl_lds16(asrc[it] + k0, &As[(it * 256 + tid) * 8]);
  };
  auto mfmaPhase = [&]() {
    #pragma unroll
    for (int kk = 0; kk < 2; kk++) {
      bf16x8 a[4], b[NF];
      int us = ((lg + kk * 4) ^ (lq & 7)) * 8;
      #pragma unroll
      for (int fi = 0; fi < 4; fi++)
        a[fi] = *(const bf16x8*)&As[(wr * 64 + fi * 16 + lq) * 64 + us];
      #pragma unroll
      for (int fj = 0; fj < NF; fj++)
        b[fj] = *(const bf16x8*)&Bs[(wc * (NF * 16) + fj * 16 + lq) * 64 + us];
      #pragma unroll
      for (int fi = 0; fi < 4; fi++)
        #pragma unroll
        for (int fj = 0; fj < NF; fj++)
          acc[fi][fj] = __builtin_amdgcn_mfma_f32_16x16x32_bf16(a[fi], b[fj], acc[fi][fj], 0, 0, 0);
    }
  };

  loadB(br0, 0);
  for (int k0 = 0; k0 < K; k0 += 128) {
    stageA(k0);
    writeB(br0);
    loadB(br1, k0 + 64);
    __syncthreads();
    mfmaPhase();
    __syncthreads();
    stageA(k0 + 64);
    writeB(br1);
    if (k0 + 128 < K) loadB(br0, k0 + 128);
    __syncthreads();
    mfmaPhase();
    __syncthreads();
  }

  #pragma unroll
  for (int fi = 0; fi < 4; fi++) {
    #pragma unroll
    for (int v = 0; v < 4; v++) {
      int r = row0 + wr * 64 + fi * 16 + lg * 4 + v;
      long orow;
      float gv = 1.f;
      if (MODE >= 2) {
        if (r >= cnt) continue;
        if (MODE == 2) orow = lbase + r;          // compact order
        else { orow = tlist[lbase + r]; gv = gate[orow]; }
      } else {
        orow = r;
      }
      #pragma unroll
      for (int fj = 0; fj < NF; fj++) {
        int c = col0 + wc * (NF * 16) + fj * 16 + lq;
        float val = acc[fi][fj][v] + bp[c];
        if (MODE == 0)      Cb[orow * N + c] = (__bf16)val;
        else if (MODE == 1) Cf[orow * N + c] += val;
        else if (MODE == 2) Cb[orow * N + c] = (__bf16)fmaxf(val, 0.f);
        else                Cf[orow * N + c] += gv * val;
      }
    }
  }
}

// ---------------------------------------------------------------- flash attention, bf16 MFMA
// QB_=128 q-rows/block, 512 thr = 8 waves, each wave owns 16 q-rows.
// Vt XOR-swizzled (col' = kv ^ ((d>>3)<<3)) -> conflict-free transpose writes.
#define SC_LOG2 0.18033688011112042f   // (1/sqrt(64)) * log2(e)
__global__ __launch_bounds__(512) void attn_mfma_kernel(const __bf16* __restrict__ qkv,
                                                        __bf16* __restrict__ out) {
  __shared__ __bf16 Ks[64][72];
  __shared__ __bf16 Vt[64][72];    // [d][kv^swz]
  __shared__ __bf16 Ps[QB_][72];   // wave-private 16-row slabs
  int tid = threadIdx.x;
  int w = tid >> 6, lane = tid & 63, lq = lane & 15, lg = lane >> 4;
  int qt = (S_ / QB_ - 1) - blockIdx.x;   // heaviest first
  int b = blockIdx.y >> 4, hh = blockIdx.y & 15;
  const __bf16* qbase = qkv + (size_t)b * S_ * 3 * D_ + hh * HD_;

  bf16x8 qa[2];
  {
    const __bf16* qp = qbase + (size_t)(qt * QB_ + w * 16 + lq) * 3 * D_ + lg * 8;
    qa[0] = *(const bf16x8*)qp;
    qa[1] = *(const bf16x8*)(qp + 32);
  }

  f32x4 o[4] = {};
  float m_[4] = {-1e30f, -1e30f, -1e30f, -1e30f};
  float l_[4] = {0.f, 0.f, 0.f, 0.f};

  int rowmin = qt * QB_ + w * 16;       // first q-row this wave owns
  int srow = tid >> 3, sc8 = tid & 7;   // staging coords (512 thr cover 64x8)
  int nkt = qt * 2 + 2;

  for (int kt = 0; kt < nkt; kt++) {
    {
      const __bf16* kp = qbase + (size_t)(kt * 64 + srow) * 3 * D_ + D_ + sc8 * 8;
      *(bf16x8*)&Ks[srow][sc8 * 8] = *(const bf16x8*)kp;
      bf16x8 vv = *(const bf16x8*)(kp + D_);
      int cs = srow ^ (sc8 << 3);
      #pragma unroll
      for (int j = 0; j < 8; j++) Vt[sc8 * 8 + j][cs] = vv[j];
    }
    __syncthreads();

    if (kt * 64 <= rowmin + 15) {       // wave active for this tile
      f32x4 s[4] = {};
      #pragma unroll
      for (int kk = 0; kk < 2; kk++)
        #pragma unroll
        for (int fc = 0; fc < 4; fc++) {
          bf16x8 kf = *(const bf16x8*)&Ks[fc * 16 + lq][lg * 8 + kk * 32];
          s[fc] = __builtin_amdgcn_mfma_f32_16x16x32_bf16(qa[kk], kf, s[fc], 0, 0, 0);
        }

      bool need_mask = (kt * 64 + 63 > rowmin);
      #pragma unroll
      for (int fc = 0; fc < 4; fc++)
        #pragma unroll
        for (int v = 0; v < 4; v++) {
          float sv = s[fc][v] * SC_LOG2;
          if (need_mask && (kt * 64 + fc * 16 + lq) > (rowmin + lg * 4 + v)) sv = -1e30f;
          s[fc][v] = sv;
        }

      #pragma unroll
      for (int v = 0; v < 4; v++) {
        float rm = fmaxf(fmaxf(s[0][v], s[1][v]), fmaxf(s[2][v], s[3][v]));
        #pragma unroll
        for (int o2 = 8; o2 >= 1; o2 >>= 1) rm = fmaxf(rm, __shfl_xor(rm, o2, 64));
        if (rm > m_[v]) {   // rescale only when the max grows (exact skip otherwise)
          float cc = exp2f(m_[v] - rm);
          m_[v] = rm;
          l_[v] *= cc;
          o[0][v] *= cc; o[1][v] *= cc; o[2][v] *= cc; o[3][v] *= cc;
        }
        float rs = 0.f;
        #pragma unroll
        for (int fc = 0; fc < 4; fc++) {
          float p = exp2f(s[fc][v] - m_[v]);
          s[fc][v] = p; rs += p;
        }
        l_[v] += rs;
        #pragma unroll
        for (int fc = 0; fc < 4; fc++)
          Ps[w * 16 + lg * 4 + v][fc * 16 + lq] = (__bf16)s[fc][v];
      }
      asm volatile("" ::: "memory");   // keep ds_writes before ds_reads (same-wave FIFO)

      #pragma unroll
      for (int kk = 0; kk < 2; kk++) {
        bf16x8 pa = *(const bf16x8*)&Ps[w * 16 + lq][lg * 8 + kk * 32];
        #pragma unroll
        for (int dc = 0; dc < 4; dc++) {
          int d = dc * 16 + lq;
          int col = (lg * 8 + kk * 32) ^ ((d >> 3) << 3);
          bf16x8 vb = *(const bf16x8*)&Vt[d][col];
          o[dc] = __builtin_amdgcn_mfma_f32_16x16x32_bf16(pa, vb, o[dc], 0, 0, 0);
        }
      }
    }
    __syncthreads();
  }

  #pragma unroll
  for (int v = 0; v < 4; v++) {
    float ls = l_[v];
    #pragma unroll
    for (int o2 = 8; o2 >= 1; o2 >>= 1) ls += __shfl_xor(ls, o2, 64);
    float inv = 1.0f / ls;
    int row = rowmin + lg * 4 + v;
    __bf16* op = out + ((size_t)b * S_ + row) * D_ + hh * HD_;
    #pragma unroll
    for (int dc = 0; dc < 4; dc++)
      op[dc * 16 + lq] = (__bf16)(o[dc][v] * inv);
  }
}

// ---------------------------------------------------------------- final mean + head (fp32)
__global__ __launch_bounds__(256) void mean_part_kernel(const float* __restrict__ X,
                                                        float* __restrict__ part) {
  int bd = blockIdx.x * 256 + threadIdx.x;
  int chunk = blockIdx.y;
  int b = bd >> 10, d = bd & 1023;
  float s = 0.f;
  #pragma unroll 4
  for (int i = 0; i < 64; i++) {
    int sidx = chunk * 64 + i;
    s += X[((size_t)b * S_ + sidx) * D_ + d];
  }
  part[chunk * T_ + bd] = s;
}

__global__ __launch_bounds__(256) void mean_final_kernel(const float* __restrict__ part,
                                                         float* __restrict__ hm) {
  int bd = blockIdx.x * 256 + threadIdx.x;
  float s = 0.f;
  #pragma unroll
  for (int c = 0; c < 16; c++) s += part[c * T_ + bd];
  hm[bd] = s * (1.0f / S_);
}

__global__ __launch_bounds__(256) void head_kernel(const float* __restrict__ hm,
    const float* __restrict__ hw, const float* __restrict__ hb,
    float* __restrict__ out) {
  int w = threadIdx.x >> 6;
  int lane = threadIdx.x & 63;
  int c = blockIdx.x * 4 + w;
  const float* row = hw + (size_t)c * D_;
  float acc0 = 0.f, acc1 = 0.f;
  #pragma unroll
  for (int k = 0; k < 4; k++) {
    int d = lane * 4 + k * 256;
    float4 wv = *(const float4*)(row + d);
    float4 h0 = *(const float4*)(hm + d);
    float4 h1 = *(const float4*)(hm + D_ + d);
    acc0 += wv.x * h0.x + wv.y * h0.y + wv.z * h0.z + wv.w * h0.w;
    acc1 += wv.x * h1.x + wv.y * h1.y + wv.z * h1.z + wv.w * h1.w;
  }
  #pragma unroll
  for (int o = 32; o >= 1; o >>= 1) {
    acc0 += __shfl_xor(acc0, o, 64);
    acc1 += __shfl_xor(acc1, o, 64);
  }
  if (lane == 0) {
    float bias = hb[c];
    out[c] = acc0 + bias;
    out[NC_ + c] = acc1 + bias;
  }
}

// ---------------------------------------------------------------- host launch
extern "C" void kernel_launch(void* const* d_in, const int* in_sizes, int n_in,
                              void* d_out, int out_size, void* d_ws, size_t ws_size,
                              hipStream_t stream) {
  const int*   x        = (const int*)d_in[0];
  const float* tok_emb  = (const float*)d_in[1];
  const float* pos_emb  = (const float*)d_in[2];
  const float* in_proj_w= (const float*)d_in[3];
  const float* in_proj_b= (const float*)d_in[4];
  const float* out_w    = (const float*)d_in[5];
  const float* out_b    = (const float*)d_in[6];
  const float* ln1_w    = (const float*)d_in[7];
  const float* ln1_b    = (const float*)d_in[8];
  const float* ln2_w    = (const float*)d_in[9];
  const float* ln2_b    = (const float*)d_in[10];
  const float* gr_w     = (const float*)d_in[11];
  const float* gr_b     = (const float*)d_in[12];
  const float* er_w     = (const float*)d_in[13];
  const float* er_b     = (const float*)d_in[14];
  const float* w1       = (const float*)d_in[15];
  const float* b1       = (const float*)d_in[16];
  const float* w2       = (const float*)d_in[17];
  const float* b2       = (const float*)d_in[18];
  const float* lnf_w    = (const float*)d_in[19];
  const float* lnf_b    = (const float*)d_in[20];
  const float* head_w   = (const float*)d_in[21];
  const float* head_b   = (const float*)d_in[22];

  char* wp = (char*)d_ws;
  auto carve = [&](size_t bytes) -> char* {
    char* p = wp;
    wp += (bytes + 255) & ~(size_t)255;
    return p;
  };
  float*  h      = (float*)carve((size_t)T_ * D_ * 4);
  float*  x1     = (float*)carve((size_t)T_ * D_ * 4);
  __bf16* x1b    = (__bf16*)carve((size_t)T_ * D_ * 2);
  __bf16* qkvb   = (__bf16*)carve((size_t)T_ * 3 * D_ * 2);
  __bf16* attnb  = (__bf16*)carve((size_t)T_ * D_ * 2);
  __bf16* hmidb  = (__bf16*)carve((size_t)T_ * H_ * 2);
  float*  part   = (float*)carve((size_t)16 * T_ * 4);
  float*  hm     = (float*)carve((size_t)B_ * D_ * 4);
  float*  gate   = (float*)carve((size_t)T_ * 4);
  int*    eidx   = (int*)carve((size_t)T_ * 4);
  int*    tlist  = (int*)carve((size_t)T_ * 4);
  int*    counts = (int*)carve(64);
  int*    offs   = (int*)carve(64);
  int*    blk    = (int*)carve(MAXBLK_ * 4);

  embed_kernel<<<T_, 256, 0, stream>>>(x, tok_emb, pos_emb, h);

  for (int l = 0; l < L_; l++) {
    // ---- attention half
    ln_kernel<false, true><<<T_, 256, 0, stream>>>(h, ln1_w + l * D_, ln1_b + l * D_,
                                                   nullptr, x1b);
    gemm_mfma<0, 4, false><<<dim3(24, 16, 1), 256, 0, stream>>>(
        x1b, in_proj_w + (size_t)l * 3 * D_ * D_, in_proj_b + (size_t)l * 3 * D_,
        nullptr, qkvb, nullptr, nullptr, nullptr, nullptr, nullptr, 3 * D_, D_);
    attn_mfma_kernel<<<dim3(S_ / QB_, B_ * NH_), 512, 0, stream>>>(qkvb, attnb);
    gemm_mfma<1, 2, false><<<dim3(16, 16, 1), 256, 0, stream>>>(
        attnb, out_w + (size_t)l * D_ * D_, out_b + (size_t)l * D_, h, nullptr,
        nullptr, nullptr, nullptr, nullptr, nullptr, D_, D_);

    // ---- MoE half (fused ln2 + route)
    ln_route_kernel<<<T_ / 4, 256, 0, stream>>>(h,
        ln2_w + l * D_, ln2_b + l * D_,
        gr_w + (size_t)l * D_ * G_, gr_b + (size_t)l * G_,
        er_w + (size_t)l * G_ * D_ * EPG_, er_b + (size_t)l * G_ * EPG_,
        x1b, eidx, gate);
    finalize_kernel<<<1, 256, 0, stream>>>(eidx, counts, offs, tlist, blk);

    gemm_mfma<2, 4, true><<<dim3(H_ / 128, MAXBLK_, 1), 256, 0, stream>>>(
        x1b, w1 + (size_t)l * NE_ * D_ * H_, b1 + (size_t)l * NE_ * H_, nullptr, hmidb,
        tlist, offs, counts, nullptr, blk, H_, D_);
    gemm_mfma<3, 2, true><<<dim3(D_ / 64, MAXBLK_, 1), 256, 0, stream>>>(
        hmidb, w2 + (size_t)l * NE_ * H_ * D_, b2 + (size_t)l * NE_ * D_, h, nullptr,
        tlist, offs, counts, gate, blk, D_, H_);
  }

  ln_kernel<true, false><<<T_, 256, 0, stream>>>(h, lnf_w, lnf_b, x1, nullptr);
  mean_part_kernel<<<dim3(B_ * D_ / 256, 16), 256, 0, stream>>>(x1, part);
  mean_final_kernel<<<B_ * D_ / 256, 256, 0, stream>>>(part, hm);
  head_kernel<<<NC_ / 4, 256, 0, stream>>>(hm, head_w, head_b, (float*)d_out);
}